// Round 4
// baseline (250.704 us; speedup 1.0000x reference)
//
#include <hip/hip_runtime.h>
#include <math.h>

#define E_DIM 1024
#define H_DIM 16
#define D_DIM 64
#define B_DIM 2
#define T_DIM 2048
#define M_TOT (B_DIM * T_DIM)   // 4096

typedef __bf16 bf16_t;
typedef bf16_t bf16x4 __attribute__((ext_vector_type(4)));
typedef bf16_t bf16x8 __attribute__((ext_vector_type(8)));
typedef float f32x4 __attribute__((ext_vector_type(4)));

#define LOG2E_DIV8 0.18033688011112042f   // 0.125 * log2(e)

__device__ __forceinline__ void load_lds16(const void* g, void* l) {
    __builtin_amdgcn_global_load_lds(
        (const __attribute__((address_space(1))) unsigned int*)g,
        (__attribute__((address_space(3))) unsigned int*)l, 16, 0, 0);
}

// ---------------------------------------------------------------------------
// Prep: cast hidden_states fp32 -> bf16
// ---------------------------------------------------------------------------
__global__ __launch_bounds__(256) void cast_x_kernel(const float* __restrict__ x,
                                                     bf16_t* __restrict__ xb) {
    size_t i = ((size_t)blockIdx.x * 256 + threadIdx.x) * 8;
    float4 a = *reinterpret_cast<const float4*>(x + i);
    float4 b = *reinterpret_cast<const float4*>(x + i + 4);
    bf16x8 o;
    o[0] = (bf16_t)a.x; o[1] = (bf16_t)a.y; o[2] = (bf16_t)a.z; o[3] = (bf16_t)a.w;
    o[4] = (bf16_t)b.x; o[5] = (bf16_t)b.y; o[6] = (bf16_t)b.z; o[7] = (bf16_t)b.w;
    *reinterpret_cast<bf16x8*>(xb + i) = o;
}

// ---------------------------------------------------------------------------
// Prep: Wcat[(z*16+h)*64 + d][e] = Wz[h][e][d], bf16. Tiled coalesced transpose.
// ---------------------------------------------------------------------------
__global__ __launch_bounds__(256) void wqkv_t_kernel(
    const float* __restrict__ Wq, const float* __restrict__ Wk,
    const float* __restrict__ Wv, bf16_t* __restrict__ Wcat) {
    const int et = blockIdx.x, h = blockIdx.y, z = blockIdx.z;
    const float* W = z == 0 ? Wq : (z == 1 ? Wk : Wv);
    __shared__ float Tt[64][65];
    const int tid = threadIdx.x;
    const int r = tid >> 2, c4 = (tid & 3) * 16;
    const float* src = W + (size_t)h * 65536 + (size_t)(et * 64 + r) * 64 + c4;
    #pragma unroll
    for (int k = 0; k < 16; k += 4) {
        float4 v = *reinterpret_cast<const float4*>(src + k);
        Tt[r][c4 + k + 0] = v.x; Tt[r][c4 + k + 1] = v.y;
        Tt[r][c4 + k + 2] = v.z; Tt[r][c4 + k + 3] = v.w;
    }
    __syncthreads();
    bf16x8 o0, o1;
    #pragma unroll
    for (int k = 0; k < 8; ++k) o0[k] = (bf16_t)Tt[c4 + k][r];
    #pragma unroll
    for (int k = 0; k < 8; ++k) o1[k] = (bf16_t)Tt[c4 + 8 + k][r];
    bf16_t* dst = Wcat + ((size_t)(z * 16 + h) * 64 + r) * 1024 + et * 64 + c4;
    *reinterpret_cast<bf16x8*>(dst) = o0;
    *reinterpret_cast<bf16x8*>(dst + 8) = o1;
}

// ---------------------------------------------------------------------------
// Prep: Wgt[e][h*64+d] = Wo[h][d][e]*gate[h], bf16
// ---------------------------------------------------------------------------
__global__ __launch_bounds__(256) void wo_t_kernel(const float* __restrict__ Wo,
                                                   const float* __restrict__ gate,
                                                   bf16_t* __restrict__ Wgt) {
    const int et = blockIdx.x, h = blockIdx.y;
    const float g = gate[h];
    __shared__ float Tt[64][65];
    const int tid = threadIdx.x;
    const int r = tid >> 2, c4 = (tid & 3) * 16;
    const float* src = Wo + (size_t)h * 65536 + (size_t)r * 1024 + et * 64 + c4;
    #pragma unroll
    for (int k = 0; k < 16; k += 4) {
        float4 v = *reinterpret_cast<const float4*>(src + k);
        Tt[r][c4 + k + 0] = v.x * g; Tt[r][c4 + k + 1] = v.y * g;
        Tt[r][c4 + k + 2] = v.z * g; Tt[r][c4 + k + 3] = v.w * g;
    }
    __syncthreads();
    bf16x8 o0, o1;
    #pragma unroll
    for (int k = 0; k < 8; ++k) o0[k] = (bf16_t)Tt[c4 + k][r];
    #pragma unroll
    for (int k = 0; k < 8; ++k) o1[k] = (bf16_t)Tt[c4 + 8 + k][r];
    bf16_t* dst = Wgt + (size_t)(et * 64 + r) * 1024 + h * 64 + c4;
    *reinterpret_cast<bf16x8*>(dst) = o0;
    *reinterpret_cast<bf16x8*>(dst + 8) = o1;
}

// ---------------------------------------------------------------------------
// Prep: bsum[e] = sum_h gate[h]*bo[h][e]
// ---------------------------------------------------------------------------
__global__ __launch_bounds__(256) void bias_sum_kernel(const float* __restrict__ bo,
                                                       const float* __restrict__ gate,
                                                       float* __restrict__ bsum) {
    int e = blockIdx.x * 256 + threadIdx.x;
    float s = 0.f;
    #pragma unroll
    for (int h = 0; h < H_DIM; ++h) s += gate[h] * bo[h * E_DIM + e];
    bsum[e] = s;
}

// ---------------------------------------------------------------------------
// Q/K GEMM: [4096 x 2048 x 1024], 128x128 tile, BK=32, 2-phase dbuf staging.
// SWAPPED mfma -> C[n][m]: lane holds 4 consecutive d -> bf16x4 stores.
// Q additionally scaled by 0.125*log2(e) (exp2-domain softmax).
// ---------------------------------------------------------------------------
__global__ __launch_bounds__(256) void qk_gemm_kernel(
    const bf16_t* __restrict__ Xb, const bf16_t* __restrict__ Wcat,
    const float* __restrict__ bqp, const float* __restrict__ bkp,
    bf16_t* __restrict__ Qw, bf16_t* __restrict__ Kw) {
    const int p = blockIdx.x;                    // 512 blocks
    const int l = (p & 7) * 64 + (p >> 3);       // bijective XCD swizzle
    const int mx = l & 31, ny = l >> 5;
    const int m0 = mx * 128, n0 = ny * 128;

    __shared__ bf16_t As[2][128][32];
    __shared__ bf16_t Bs[2][128][32];

    const int tid = threadIdx.x;
    const int lane = tid & 63, wid = tid >> 6;
    const int wr = wid >> 1, wc = wid & 1;
    const int lr = lane & 15, lg = lane >> 4;
    const int srow = lane >> 2, scol = (lane & 3) * 8;

    f32x4 acc[4][4] = {};

    #define STAGE_QK(buf, k0)                                                      \
        _Pragma("unroll")                                                          \
        for (int j = 0; j < 2; ++j) {                                              \
            load_lds16(Xb + (size_t)(m0 + wid * 32 + j * 16 + srow) * E_DIM + (k0) + scol, \
                       (char*)&As[buf][0][0] + wid * 2048 + j * 1024);             \
            load_lds16(Wcat + (size_t)(n0 + wid * 32 + j * 16 + srow) * E_DIM + (k0) + scol, \
                       (char*)&Bs[buf][0][0] + wid * 2048 + j * 1024);             \
        }

    STAGE_QK(0, 0);
    for (int t = 0; t < 32; ++t) {
        __syncthreads();                          // implicit vmcnt(0): buf[t&1] ready
        if (t < 31) STAGE_QK((t + 1) & 1, (t + 1) * 32);
        const int b = t & 1;
        bf16x8 a[4], bb[4];
        #pragma unroll
        for (int i = 0; i < 4; ++i)
            a[i] = *reinterpret_cast<const bf16x8*>(&As[b][wr * 64 + i * 16 + lr][lg * 8]);
        #pragma unroll
        for (int j = 0; j < 4; ++j)
            bb[j] = *reinterpret_cast<const bf16x8*>(&Bs[b][wc * 64 + j * 16 + lr][lg * 8]);
        __builtin_amdgcn_s_setprio(1);
        #pragma unroll
        for (int j = 0; j < 4; ++j)
            #pragma unroll
            for (int i = 0; i < 4; ++i)
                acc[j][i] = __builtin_amdgcn_mfma_f32_16x16x32_bf16(bb[j], a[i], acc[j][i], 0, 0, 0);
        __builtin_amdgcn_s_setprio(0);
    }
    #undef STAGE_QK

    const int z = n0 >> 10;                       // 0 = Q, 1 = K (block-uniform)
    const float scale = (z == 0) ? LOG2E_DIV8 : 1.0f;
    const float* bias = (z == 0) ? bqp : bkp;
    bf16_t* Obase = (z == 0) ? Qw : Kw;
    const int b_idx = m0 >> 11;
    const int t00 = m0 & (T_DIM - 1);

    #pragma unroll
    for (int j = 0; j < 4; ++j) {
        const int n = n0 + wc * 64 + j * 16 + lg * 4;   // + r
        const int h = (n >> 6) & 15;
        const int dbase = (n & 63);
        const float4 bv4 = *reinterpret_cast<const float4*>(&bias[n & 1023]);
        bf16_t* O = Obase + (size_t)(b_idx * H_DIM + h) * T_DIM * 64;
        #pragma unroll
        for (int i = 0; i < 4; ++i) {
            const int t = t00 + wr * 64 + i * 16 + lr;
            bf16x4 t4;
            #pragma unroll
            for (int r = 0; r < 4; ++r)
                t4[r] = (bf16_t)((acc[j][i][r] + (&bv4.x)[r]) * scale);
            *reinterpret_cast<bf16x4*>(&O[(size_t)t * 64 + dbase]) = t4;
        }
    }
}

// ---------------------------------------------------------------------------
// V GEMM: [4096 x 1024 x 1024], unswapped (t-contiguous per lane) so the
// transposed V write Vt[d][t..t+4] is an 8B store.
// ---------------------------------------------------------------------------
__global__ __launch_bounds__(256) void v_gemm_kernel(
    const bf16_t* __restrict__ Xb, const bf16_t* __restrict__ Wcat,
    const float* __restrict__ bvp, bf16_t* __restrict__ Vtw) {
    const int p = blockIdx.x;                    // 256 blocks
    const int l = (p & 7) * 32 + (p >> 3);
    const int mx = l & 31, ny = l >> 5;
    const int m0 = mx * 128, n0 = ny * 128;
    const bf16_t* Wv = Wcat + (size_t)2048 * E_DIM;

    __shared__ bf16_t As[2][128][32];
    __shared__ bf16_t Bs[2][128][32];

    const int tid = threadIdx.x;
    const int lane = tid & 63, wid = tid >> 6;
    const int wr = wid >> 1, wc = wid & 1;
    const int lr = lane & 15, lg = lane >> 4;
    const int srow = lane >> 2, scol = (lane & 3) * 8;

    f32x4 acc[4][4] = {};

    #define STAGE_V(buf, k0)                                                       \
        _Pragma("unroll")                                                          \
        for (int j = 0; j < 2; ++j) {                                              \
            load_lds16(Xb + (size_t)(m0 + wid * 32 + j * 16 + srow) * E_DIM + (k0) + scol, \
                       (char*)&As[buf][0][0] + wid * 2048 + j * 1024);             \
            load_lds16(Wv + (size_t)(n0 + wid * 32 + j * 16 + srow) * E_DIM + (k0) + scol, \
                       (char*)&Bs[buf][0][0] + wid * 2048 + j * 1024);             \
        }

    STAGE_V(0, 0);
    for (int t = 0; t < 32; ++t) {
        __syncthreads();
        if (t < 31) STAGE_V((t + 1) & 1, (t + 1) * 32);
        const int b = t & 1;
        bf16x8 a[4], bb[4];
        #pragma unroll
        for (int i = 0; i < 4; ++i)
            a[i] = *reinterpret_cast<const bf16x8*>(&As[b][wr * 64 + i * 16 + lr][lg * 8]);
        #pragma unroll
        for (int j = 0; j < 4; ++j)
            bb[j] = *reinterpret_cast<const bf16x8*>(&Bs[b][wc * 64 + j * 16 + lr][lg * 8]);
        __builtin_amdgcn_s_setprio(1);
        #pragma unroll
        for (int i = 0; i < 4; ++i)
            #pragma unroll
            for (int j = 0; j < 4; ++j)
                acc[i][j] = __builtin_amdgcn_mfma_f32_16x16x32_bf16(a[i], bb[j], acc[i][j], 0, 0, 0);
        __builtin_amdgcn_s_setprio(0);
    }
    #undef STAGE_V

    const int b_idx = m0 >> 11;
    const int t00 = m0 & (T_DIM - 1);
    #pragma unroll
    for (int j = 0; j < 4; ++j) {
        const int n = n0 + wc * 64 + j * 16 + lr;
        const int h = (n >> 6) & 15;
        const int d = n & 63;
        const float bval = bvp[n];
        bf16_t* O = Vtw + (size_t)(b_idx * H_DIM + h) * 64 * T_DIM + (size_t)d * T_DIM;
        #pragma unroll
        for (int i = 0; i < 4; ++i) {
            const int t = t00 + wr * 64 + i * 16 + lg * 4;
            bf16x4 t4;
            #pragma unroll
            for (int r = 0; r < 4; ++r) t4[r] = (bf16_t)(acc[i][j][r] + bval);
            *reinterpret_cast<bf16x4*>(&O[t]) = t4;
        }
    }
}

// ---------------------------------------------------------------------------
// Flash attention: 8 waves x 16 q-rows, KVBLK=128, swapped QK^T AND swapped PV
// (q is lane-local everywhere: no shuffles for rescale/normalize). exp2-domain
// softmax (Q pre-scaled by 0.125*log2e). T14: next K/V tile loaded to regs at
// loop top, written to LDS after the post-PV barrier.
// ---------------------------------------------------------------------------
__global__ __launch_bounds__(512, 4) void attn_mfma_kernel(
    const bf16_t* __restrict__ Q, const bf16_t* __restrict__ K,
    const bf16_t* __restrict__ Vt, bf16_t* __restrict__ Aw) {
    const int p = blockIdx.x;                    // 512 blocks
    const int l = (p & 7) * 64 + (p >> 3);       // XCD swizzle: 4 heads/XCD
    const int qx = l & 15, bh = l >> 4;
    const int b_idx = bh >> 4, h = bh & 15;
    const int q0 = qx * 128;
    const size_t base = (size_t)bh * T_DIM * 64;

    __shared__ bf16_t Ks[128][72];
    __shared__ bf16_t Vs[64][136];
    __shared__ bf16_t Ps[8][16][136];

    const int tid = threadIdx.x;
    const int lane = tid & 63;
    const int wid = tid >> 6;
    const int lr = lane & 15, lg = lane >> 4;

    // Q fragments (B-operand of QK^T): lane holds Q[q0+wid*16+lr][kc*32+lg*8..]
    bf16x8 bq[2];
    #pragma unroll
    for (int kc = 0; kc < 2; ++kc)
        bq[kc] = *reinterpret_cast<const bf16x8*>(
            Q + base + (size_t)(q0 + wid * 16 + lr) * 64 + kc * 32 + lg * 8);

    // staging indices
    const int kr = tid >> 2, kc0 = (tid & 3) * 16;
    const int vr = tid >> 3, vc0 = (tid & 7) * 16;

    // prologue: stage tile 0
    bf16x8 kA, kB, vA, vB;
    {
        const bf16_t* ksrc = K + base + (size_t)kr * 64 + kc0;
        kA = *reinterpret_cast<const bf16x8*>(ksrc);
        kB = *reinterpret_cast<const bf16x8*>(ksrc + 8);
        const bf16_t* vsrc = Vt + base + (size_t)vr * T_DIM + vc0;
        vA = *reinterpret_cast<const bf16x8*>(vsrc);
        vB = *reinterpret_cast<const bf16x8*>(vsrc + 8);
        *reinterpret_cast<bf16x8*>(&Ks[kr][kc0])     = kA;
        *reinterpret_cast<bf16x8*>(&Ks[kr][kc0 + 8]) = kB;
        *reinterpret_cast<bf16x8*>(&Vs[vr][vc0])     = vA;
        *reinterpret_cast<bf16x8*>(&Vs[vr][vc0 + 8]) = vB;
    }
    __syncthreads();

    float mreg = -INFINITY, lrow = 0.f;
    f32x4 o[4] = {};                              // o[db]: d = db*16+lg*4+r, q = lr

    for (int s0 = 0; s0 < T_DIM; s0 += 128) {
        const bool more = (s0 + 128) < T_DIM;
        if (more) {                               // T14: issue next-tile loads now
            const bf16_t* ksrc = K + base + (size_t)(s0 + 128 + kr) * 64 + kc0;
            kA = *reinterpret_cast<const bf16x8*>(ksrc);
            kB = *reinterpret_cast<const bf16x8*>(ksrc + 8);
            const bf16_t* vsrc = Vt + base + (size_t)vr * T_DIM + s0 + 128 + vc0;
            vA = *reinterpret_cast<const bf16x8*>(vsrc);
            vB = *reinterpret_cast<const bf16x8*>(vsrc + 8);
        }

        // S^T = mfma(K, Q): lane -> q = lr, s = kb*16 + lg*4 + r
        f32x4 s[8] = {};
        __builtin_amdgcn_s_setprio(1);
        #pragma unroll
        for (int kb = 0; kb < 8; ++kb)
            #pragma unroll
            for (int kc = 0; kc < 2; ++kc) {
                bf16x8 ak = *reinterpret_cast<const bf16x8*>(&Ks[kb * 16 + lr][kc * 32 + lg * 8]);
                s[kb] = __builtin_amdgcn_mfma_f32_16x16x32_bf16(ak, bq[kc], s[kb], 0, 0, 0);
            }
        __builtin_amdgcn_s_setprio(0);

        // row max (own 32, then across lg-groups)
        float pmax = -INFINITY;
        #pragma unroll
        for (int kb = 0; kb < 8; ++kb) {
            float m01 = fmaxf(s[kb][0], s[kb][1]);
            float m23 = fmaxf(s[kb][2], s[kb][3]);
            pmax = fmaxf(pmax, fmaxf(m01, m23));
        }
        pmax = fmaxf(pmax, __shfl_xor(pmax, 16));
        pmax = fmaxf(pmax, __shfl_xor(pmax, 32));

        if (__any(pmax > mreg + 11.5f)) {         // defer-max (log2 domain)
            float newm = fmaxf(mreg, pmax);
            float alpha = exp2f(mreg - newm);
            mreg = newm;
            lrow *= alpha;
            #pragma unroll
            for (int db = 0; db < 4; ++db) o[db] *= alpha;   // q = lr: lane-uniform
        }

        // P = exp2(s - m); row sum; pack to wave-local LDS
        float rs = 0.f;
        #pragma unroll
        for (int kb = 0; kb < 8; ++kb) {
            bf16x4 t4;
            #pragma unroll
            for (int r = 0; r < 4; ++r) {
                float pv = exp2f(s[kb][r] - mreg);
                rs += pv;
                t4[r] = (bf16_t)pv;
            }
            *reinterpret_cast<bf16x4*>(&Ps[wid][lr][kb * 16 + lg * 4]) = t4;
        }
        rs += __shfl_xor(rs, 16);
        rs += __shfl_xor(rs, 32);
        lrow += rs;

        // O^T += V^T P^T: swapped PV -> lane holds d = db*16+lg*4+r, q = lr
        __builtin_amdgcn_s_setprio(1);
        #pragma unroll
        for (int sc = 0; sc < 4; ++sc) {
            bf16x8 bp = *reinterpret_cast<const bf16x8*>(&Ps[wid][lr][sc * 32 + lg * 8]);
            #pragma unroll
            for (int db = 0; db < 4; ++db) {
                bf16x8 av = *reinterpret_cast<const bf16x8*>(&Vs[db * 16 + lr][sc * 32 + lg * 8]);
                o[db] = __builtin_amdgcn_mfma_f32_16x16x32_bf16(av, bp, o[db], 0, 0, 0);
            }
        }
        __builtin_amdgcn_s_setprio(0);
        __syncthreads();                          // all reads of Ks/Vs done

        if (more) {                               // write prefetched regs -> LDS
            *reinterpret_cast<bf16x8*>(&Ks[kr][kc0])     = kA;
            *reinterpret_cast<bf16x8*>(&Ks[kr][kc0 + 8]) = kB;
            *reinterpret_cast<bf16x8*>(&Vs[vr][vc0])     = vA;
            *reinterpret_cast<bf16x8*>(&Vs[vr][vc0 + 8]) = vB;
        }
        __syncthreads();                          // staging visible
    }

    // epilogue: q = lr is lane-local -> no shuffles
    const float linv = 1.f / lrow;
    const int t = q0 + wid * 16 + lr;
    const size_t rowbase = ((size_t)b_idx * T_DIM + t) * E_DIM + h * 64;
    #pragma unroll
    for (int db = 0; db < 4; ++db) {
        bf16x4 t4;
        #pragma unroll
        for (int r = 0; r < 4; ++r) t4[r] = (bf16_t)(o[db][r] * linv);
        *reinterpret_cast<bf16x4*>(&Aw[rowbase + db * 16 + lg * 4]) = t4;
    }
}

// ---------------------------------------------------------------------------
// Output GEMM: [4096 x 1024 x 1024], swapped -> float4 stores, 2-phase dbuf.
// ---------------------------------------------------------------------------
__global__ __launch_bounds__(256) void out_gemm_kernel(
    const bf16_t* __restrict__ Aw, const bf16_t* __restrict__ Wgt,
    const float* __restrict__ bsum, float* __restrict__ out) {
    const int p = blockIdx.x;                    // 256 blocks
    const int l = (p & 7) * 32 + (p >> 3);
    const int mx = l & 31, ny = l >> 5;
    const int m0 = mx * 128, n0 = ny * 128;

    __shared__ bf16_t As[2][128][32];
    __shared__ bf16_t Bs[2][128][32];

    const int tid = threadIdx.x;
    const int lane = tid & 63, wid = tid >> 6;
    const int wr = wid >> 1, wc = wid & 1;
    const int lr = lane & 15, lg = lane >> 4;
    const int srow = lane >> 2, scol = (lane & 3) * 8;

    f32x4 acc[4][4] = {};

    #define STAGE_O(buf, k0)                                                       \
        _Pragma("unroll")                                                          \
        for (int j = 0; j < 2; ++j) {                                              \
            load_lds16(Aw + (size_t)(m0 + wid * 32 + j * 16 + srow) * E_DIM + (k0) + scol, \
                       (char*)&As[buf][0][0] + wid * 2048 + j * 1024);             \
            load_lds16(Wgt + (size_t)(n0 + wid * 32 + j * 16 + srow) * E_DIM + (k0) + scol, \
                       (char*)&Bs[buf][0][0] + wid * 2048 + j * 1024);             \
        }

    STAGE_O(0, 0);
    for (int t = 0; t < 32; ++t) {
        __syncthreads();
        if (t < 31) STAGE_O((t + 1) & 1, (t + 1) * 32);
        const int b = t & 1;
        bf16x8 a[4], bb[4];
        #pragma unroll
        for (int i = 0; i < 4; ++i)
            a[i] = *reinterpret_cast<const bf16x8*>(&As[b][wr * 64 + i * 16 + lr][lg * 8]);
        #pragma unroll
        for (int j = 0; j < 4; ++j)
            bb[j] = *reinterpret_cast<const bf16x8*>(&Bs[b][wc * 64 + j * 16 + lr][lg * 8]);
        __builtin_amdgcn_s_setprio(1);
        #pragma unroll
        for (int j = 0; j < 4; ++j)
            #pragma unroll
            for (int i = 0; i < 4; ++i)
                acc[j][i] = __builtin_amdgcn_mfma_f32_16x16x32_bf16(bb[j], a[i], acc[j][i], 0, 0, 0);
        __builtin_amdgcn_s_setprio(0);
    }
    #undef STAGE_O

    #pragma unroll
    for (int j = 0; j < 4; ++j) {
        const int e = n0 + wc * 64 + j * 16 + lg * 4;
        const float4 bs4 = *reinterpret_cast<const float4*>(&bsum[e]);
        #pragma unroll
        for (int i = 0; i < 4; ++i) {
            const int m = m0 + wr * 64 + i * 16 + lr;
            float4 o4;
            o4.x = acc[j][i][0] + bs4.x;
            o4.y = acc[j][i][1] + bs4.y;
            o4.z = acc[j][i][2] + bs4.z;
            o4.w = acc[j][i][3] + bs4.w;
            *reinterpret_cast<float4*>(&out[(size_t)m * E_DIM + e]) = o4;
        }
    }
}

// ---------------------------------------------------------------------------
extern "C" void kernel_launch(void* const* d_in, const int* in_sizes, int n_in,
                              void* d_out, int out_size, void* d_ws, size_t ws_size,
                              hipStream_t stream) {
    const float* hs   = (const float*)d_in[0];
    const float* Wq   = (const float*)d_in[1];
    const float* bq   = (const float*)d_in[2];
    const float* Wk   = (const float*)d_in[3];
    const float* bk   = (const float*)d_in[4];
    const float* Wv   = (const float*)d_in[5];
    const float* bv   = (const float*)d_in[6];
    const float* Wo   = (const float*)d_in[7];
    const float* bo   = (const float*)d_in[8];
    const float* gate = (const float*)d_in[9];
    float* out = (float*)d_out;

    const size_t NX = (size_t)M_TOT * E_DIM;           // 4M elems
    const size_t NW = (size_t)H_DIM * D_DIM * E_DIM;   // 1M elems
    bf16_t* p = (bf16_t*)d_ws;
    bf16_t* Xb   = p; p += NX;
    bf16_t* Wcat = p; p += 3 * NW;
    bf16_t* Wgt  = p; p += NW;
    bf16_t* Qw   = p; p += NX;
    bf16_t* Kw   = p; p += NX;
    bf16_t* Vtw  = p; p += NX;
    bf16_t* Aw   = p; p += NX;
    float*  bsum = (float*)p;

    cast_x_kernel<<<dim3(NX / 2048), 256, 0, stream>>>(hs, Xb);
    wqkv_t_kernel<<<dim3(16, 16, 3), 256, 0, stream>>>(Wq, Wk, Wv, Wcat);
    wo_t_kernel<<<dim3(16, 16), 256, 0, stream>>>(Wo, gate, Wgt);
    bias_sum_kernel<<<dim3(4), 256, 0, stream>>>(bo, gate, bsum);

    qk_gemm_kernel<<<dim3(512), 256, 0, stream>>>(Xb, Wcat, bq, bk, Qw, Kw);
    v_gemm_kernel<<<dim3(256), 256, 0, stream>>>(Xb, Wcat, bv, Vtw);

    attn_mfma_kernel<<<dim3(512), 512, 0, stream>>>(Qw, Kw, Vtw, Aw);

    out_gemm_kernel<<<dim3(256), 256, 0, stream>>>(Aw, Wgt, bsum, out);
}

// Round 5
// 245.783 us; speedup vs baseline: 1.0200x; 1.0200x over previous
//
#include <hip/hip_runtime.h>
#include <math.h>

#define E_DIM 1024
#define H_DIM 16
#define D_DIM 64
#define B_DIM 2
#define T_DIM 2048
#define M_TOT (B_DIM * T_DIM)   // 4096

typedef __bf16 bf16_t;
typedef bf16_t bf16x4 __attribute__((ext_vector_type(4)));
typedef bf16_t bf16x8 __attribute__((ext_vector_type(8)));
typedef float f32x4 __attribute__((ext_vector_type(4)));

#define LOG2E_DIV8 0.18033688011112042f   // 0.125 * log2(e)

__device__ __forceinline__ float fast_exp2(float x) {
#if __has_builtin(__builtin_amdgcn_exp2f)
    return __builtin_amdgcn_exp2f(x);     // single v_exp_f32 (hw exp IS exp2)
#else
    return __expf(x * 0.6931471805599453f);
#endif
}

__device__ __forceinline__ void load_lds16(const void* g, void* l) {
    __builtin_amdgcn_global_load_lds(
        (const __attribute__((address_space(1))) unsigned int*)g,
        (__attribute__((address_space(3))) unsigned int*)l, 16, 0, 0);
}

// ---------------------------------------------------------------------------
// Prep: cast hidden_states fp32 -> bf16
// ---------------------------------------------------------------------------
__global__ __launch_bounds__(256) void cast_x_kernel(const float* __restrict__ x,
                                                     bf16_t* __restrict__ xb) {
    size_t i = ((size_t)blockIdx.x * 256 + threadIdx.x) * 8;
    float4 a = *reinterpret_cast<const float4*>(x + i);
    float4 b = *reinterpret_cast<const float4*>(x + i + 4);
    bf16x8 o;
    o[0] = (bf16_t)a.x; o[1] = (bf16_t)a.y; o[2] = (bf16_t)a.z; o[3] = (bf16_t)a.w;
    o[4] = (bf16_t)b.x; o[5] = (bf16_t)b.y; o[6] = (bf16_t)b.z; o[7] = (bf16_t)b.w;
    *reinterpret_cast<bf16x8*>(xb + i) = o;
}

// ---------------------------------------------------------------------------
// Prep: Wcat[(z*16+h)*64 + d][e] = Wz[h][e][d], bf16. Tiled coalesced transpose.
// ---------------------------------------------------------------------------
__global__ __launch_bounds__(256) void wqkv_t_kernel(
    const float* __restrict__ Wq, const float* __restrict__ Wk,
    const float* __restrict__ Wv, bf16_t* __restrict__ Wcat) {
    const int et = blockIdx.x, h = blockIdx.y, z = blockIdx.z;
    const float* W = z == 0 ? Wq : (z == 1 ? Wk : Wv);
    __shared__ float Tt[64][65];
    const int tid = threadIdx.x;
    const int r = tid >> 2, c4 = (tid & 3) * 16;
    const float* src = W + (size_t)h * 65536 + (size_t)(et * 64 + r) * 64 + c4;
    #pragma unroll
    for (int k = 0; k < 16; k += 4) {
        float4 v = *reinterpret_cast<const float4*>(src + k);
        Tt[r][c4 + k + 0] = v.x; Tt[r][c4 + k + 1] = v.y;
        Tt[r][c4 + k + 2] = v.z; Tt[r][c4 + k + 3] = v.w;
    }
    __syncthreads();
    bf16x8 o0, o1;
    #pragma unroll
    for (int k = 0; k < 8; ++k) o0[k] = (bf16_t)Tt[c4 + k][r];
    #pragma unroll
    for (int k = 0; k < 8; ++k) o1[k] = (bf16_t)Tt[c4 + 8 + k][r];
    bf16_t* dst = Wcat + ((size_t)(z * 16 + h) * 64 + r) * 1024 + et * 64 + c4;
    *reinterpret_cast<bf16x8*>(dst) = o0;
    *reinterpret_cast<bf16x8*>(dst + 8) = o1;
}

// ---------------------------------------------------------------------------
// Prep: Wgt[e][h*64+d] = Wo[h][d][e]*gate[h], bf16
// ---------------------------------------------------------------------------
__global__ __launch_bounds__(256) void wo_t_kernel(const float* __restrict__ Wo,
                                                   const float* __restrict__ gate,
                                                   bf16_t* __restrict__ Wgt) {
    const int et = blockIdx.x, h = blockIdx.y;
    const float g = gate[h];
    __shared__ float Tt[64][65];
    const int tid = threadIdx.x;
    const int r = tid >> 2, c4 = (tid & 3) * 16;
    const float* src = Wo + (size_t)h * 65536 + (size_t)r * 1024 + et * 64 + c4;
    #pragma unroll
    for (int k = 0; k < 16; k += 4) {
        float4 v = *reinterpret_cast<const float4*>(src + k);
        Tt[r][c4 + k + 0] = v.x * g; Tt[r][c4 + k + 1] = v.y * g;
        Tt[r][c4 + k + 2] = v.z * g; Tt[r][c4 + k + 3] = v.w * g;
    }
    __syncthreads();
    bf16x8 o0, o1;
    #pragma unroll
    for (int k = 0; k < 8; ++k) o0[k] = (bf16_t)Tt[c4 + k][r];
    #pragma unroll
    for (int k = 0; k < 8; ++k) o1[k] = (bf16_t)Tt[c4 + 8 + k][r];
    bf16_t* dst = Wgt + (size_t)(et * 64 + r) * 1024 + h * 64 + c4;
    *reinterpret_cast<bf16x8*>(dst) = o0;
    *reinterpret_cast<bf16x8*>(dst + 8) = o1;
}

// ---------------------------------------------------------------------------
// Prep: bsum[e] = sum_h gate[h]*bo[h][e]
// ---------------------------------------------------------------------------
__global__ __launch_bounds__(256) void bias_sum_kernel(const float* __restrict__ bo,
                                                       const float* __restrict__ gate,
                                                       float* __restrict__ bsum) {
    int e = blockIdx.x * 256 + threadIdx.x;
    float s = 0.f;
    #pragma unroll
    for (int h = 0; h < H_DIM; ++h) s += gate[h] * bo[h * E_DIM + e];
    bsum[e] = s;
}

// ---------------------------------------------------------------------------
// Q/K GEMM: [4096 x 2048 x 1024], 128x128 tile, BK=32, 2-phase dbuf staging.
// SWAPPED mfma -> C[n][m]: lane holds 4 consecutive d -> bf16x4 stores.
// Q additionally scaled by 0.125*log2(e) (exp2-domain softmax).
// ---------------------------------------------------------------------------
__global__ __launch_bounds__(256) void qk_gemm_kernel(
    const bf16_t* __restrict__ Xb, const bf16_t* __restrict__ Wcat,
    const float* __restrict__ bqp, const float* __restrict__ bkp,
    bf16_t* __restrict__ Qw, bf16_t* __restrict__ Kw) {
    const int p = blockIdx.x;                    // 512 blocks
    const int l = (p & 7) * 64 + (p >> 3);       // bijective XCD swizzle
    const int mx = l & 31, ny = l >> 5;
    const int m0 = mx * 128, n0 = ny * 128;

    __shared__ bf16_t As[2][128][32];
    __shared__ bf16_t Bs[2][128][32];

    const int tid = threadIdx.x;
    const int lane = tid & 63, wid = tid >> 6;
    const int wr = wid >> 1, wc = wid & 1;
    const int lr = lane & 15, lg = lane >> 4;
    const int srow = lane >> 2, scol = (lane & 3) * 8;

    f32x4 acc[4][4] = {};

    #define STAGE_QK(buf, k0)                                                      \
        _Pragma("unroll")                                                          \
        for (int j = 0; j < 2; ++j) {                                              \
            load_lds16(Xb + (size_t)(m0 + wid * 32 + j * 16 + srow) * E_DIM + (k0) + scol, \
                       (char*)&As[buf][0][0] + wid * 2048 + j * 1024);             \
            load_lds16(Wcat + (size_t)(n0 + wid * 32 + j * 16 + srow) * E_DIM + (k0) + scol, \
                       (char*)&Bs[buf][0][0] + wid * 2048 + j * 1024);             \
        }

    STAGE_QK(0, 0);
    for (int t = 0; t < 32; ++t) {
        __syncthreads();                          // implicit vmcnt(0): buf[t&1] ready
        if (t < 31) STAGE_QK((t + 1) & 1, (t + 1) * 32);
        const int b = t & 1;
        bf16x8 a[4], bb[4];
        #pragma unroll
        for (int i = 0; i < 4; ++i)
            a[i] = *reinterpret_cast<const bf16x8*>(&As[b][wr * 64 + i * 16 + lr][lg * 8]);
        #pragma unroll
        for (int j = 0; j < 4; ++j)
            bb[j] = *reinterpret_cast<const bf16x8*>(&Bs[b][wc * 64 + j * 16 + lr][lg * 8]);
        __builtin_amdgcn_s_setprio(1);
        #pragma unroll
        for (int j = 0; j < 4; ++j)
            #pragma unroll
            for (int i = 0; i < 4; ++i)
                acc[j][i] = __builtin_amdgcn_mfma_f32_16x16x32_bf16(bb[j], a[i], acc[j][i], 0, 0, 0);
        __builtin_amdgcn_s_setprio(0);
    }
    #undef STAGE_QK

    const int z = n0 >> 10;                       // 0 = Q, 1 = K (block-uniform)
    const float scale = (z == 0) ? LOG2E_DIV8 : 1.0f;
    const float* bias = (z == 0) ? bqp : bkp;
    bf16_t* Obase = (z == 0) ? Qw : Kw;
    const int b_idx = m0 >> 11;
    const int t00 = m0 & (T_DIM - 1);

    #pragma unroll
    for (int j = 0; j < 4; ++j) {
        const int n = n0 + wc * 64 + j * 16 + lg * 4;   // + r
        const int h = (n >> 6) & 15;
        const int dbase = (n & 63);
        const float4 bv4 = *reinterpret_cast<const float4*>(&bias[n & 1023]);
        bf16_t* O = Obase + (size_t)(b_idx * H_DIM + h) * T_DIM * 64;
        #pragma unroll
        for (int i = 0; i < 4; ++i) {
            const int t = t00 + wr * 64 + i * 16 + lr;
            bf16x4 t4;
            #pragma unroll
            for (int r = 0; r < 4; ++r)
                t4[r] = (bf16_t)((acc[j][i][r] + (&bv4.x)[r]) * scale);
            *reinterpret_cast<bf16x4*>(&O[(size_t)t * 64 + dbase]) = t4;
        }
    }
}

// ---------------------------------------------------------------------------
// V GEMM: [4096 x 1024 x 1024], unswapped (t-contiguous per lane) so the
// transposed V write Vt[d][t..t+4] is an 8B store.
// ---------------------------------------------------------------------------
__global__ __launch_bounds__(256) void v_gemm_kernel(
    const bf16_t* __restrict__ Xb, const bf16_t* __restrict__ Wcat,
    const float* __restrict__ bvp, bf16_t* __restrict__ Vtw) {
    const int p = blockIdx.x;                    // 256 blocks
    const int l = (p & 7) * 32 + (p >> 3);
    const int mx = l & 31, ny = l >> 5;
    const int m0 = mx * 128, n0 = ny * 128;
    const bf16_t* Wv = Wcat + (size_t)2048 * E_DIM;

    __shared__ bf16_t As[2][128][32];
    __shared__ bf16_t Bs[2][128][32];

    const int tid = threadIdx.x;
    const int lane = tid & 63, wid = tid >> 6;
    const int wr = wid >> 1, wc = wid & 1;
    const int lr = lane & 15, lg = lane >> 4;
    const int srow = lane >> 2, scol = (lane & 3) * 8;

    f32x4 acc[4][4] = {};

    #define STAGE_V(buf, k0)                                                       \
        _Pragma("unroll")                                                          \
        for (int j = 0; j < 2; ++j) {                                              \
            load_lds16(Xb + (size_t)(m0 + wid * 32 + j * 16 + srow) * E_DIM + (k0) + scol, \
                       (char*)&As[buf][0][0] + wid * 2048 + j * 1024);             \
            load_lds16(Wv + (size_t)(n0 + wid * 32 + j * 16 + srow) * E_DIM + (k0) + scol, \
                       (char*)&Bs[buf][0][0] + wid * 2048 + j * 1024);             \
        }

    STAGE_V(0, 0);
    for (int t = 0; t < 32; ++t) {
        __syncthreads();
        if (t < 31) STAGE_V((t + 1) & 1, (t + 1) * 32);
        const int b = t & 1;
        bf16x8 a[4], bb[4];
        #pragma unroll
        for (int i = 0; i < 4; ++i)
            a[i] = *reinterpret_cast<const bf16x8*>(&As[b][wr * 64 + i * 16 + lr][lg * 8]);
        #pragma unroll
        for (int j = 0; j < 4; ++j)
            bb[j] = *reinterpret_cast<const bf16x8*>(&Bs[b][wc * 64 + j * 16 + lr][lg * 8]);
        __builtin_amdgcn_s_setprio(1);
        #pragma unroll
        for (int i = 0; i < 4; ++i)
            #pragma unroll
            for (int j = 0; j < 4; ++j)
                acc[i][j] = __builtin_amdgcn_mfma_f32_16x16x32_bf16(a[i], bb[j], acc[i][j], 0, 0, 0);
        __builtin_amdgcn_s_setprio(0);
    }
    #undef STAGE_V

    const int b_idx = m0 >> 11;
    const int t00 = m0 & (T_DIM - 1);
    #pragma unroll
    for (int j = 0; j < 4; ++j) {
        const int n = n0 + wc * 64 + j * 16 + lr;
        const int h = (n >> 6) & 15;
        const int d = n & 63;
        const float bval = bvp[n];
        bf16_t* O = Vtw + (size_t)(b_idx * H_DIM + h) * 64 * T_DIM + (size_t)d * T_DIM;
        #pragma unroll
        for (int i = 0; i < 4; ++i) {
            const int t = t00 + wr * 64 + i * 16 + lg * 4;
            bf16x4 t4;
            #pragma unroll
            for (int r = 0; r < 4; ++r) t4[r] = (bf16_t)(acc[i][j][r] + bval);
            *reinterpret_cast<bf16x4*>(&O[t]) = t4;
        }
    }
}

// ---------------------------------------------------------------------------
// Flash attention: 8 waves x 16 q-rows, KVBLK=128, swapped QK^T AND swapped PV
// (q = lane&15 everywhere: no shuffles for rescale/normalize). exp2-domain
// softmax via raw v_exp_f32. T14: next K/V tile loaded to regs at loop top,
// written to LDS after the post-PV barrier. Co-resident blocks stagger their
// s-tile start (online softmax is order-invariant) to overlap MFMA with VALU.
// ---------------------------------------------------------------------------
__global__ __launch_bounds__(512, 4) void attn_mfma_kernel(
    const bf16_t* __restrict__ Q, const bf16_t* __restrict__ K,
    const bf16_t* __restrict__ Vt, bf16_t* __restrict__ Aw) {
    const int p = blockIdx.x;                    // 512 blocks
    const int l = (p & 7) * 64 + (p >> 3);       // XCD swizzle: 4 heads/XCD
    const int qx = l & 15, bh = l >> 4;
    const int b_idx = bh >> 4, h = bh & 15;
    const int q0 = qx * 128;
    const size_t base = (size_t)bh * T_DIM * 64;
    const int tstart = (qx & 1) << 3;             // stagger: odd q-blocks +8 tiles

    __shared__ bf16_t Ks[128][72];
    __shared__ bf16_t Vs[64][136];
    __shared__ bf16_t Ps[8][16][136];

    const int tid = threadIdx.x;
    const int lane = tid & 63;
    const int wid = tid >> 6;
    const int lr = lane & 15, lg = lane >> 4;

    // Q fragments (B-operand of QK^T): lane holds Q[q0+wid*16+lr][kc*32+lg*8..]
    bf16x8 bq[2];
    #pragma unroll
    for (int kc = 0; kc < 2; ++kc)
        bq[kc] = *reinterpret_cast<const bf16x8*>(
            Q + base + (size_t)(q0 + wid * 16 + lr) * 64 + kc * 32 + lg * 8);

    // staging indices
    const int kr = tid >> 2, kc0 = (tid & 3) * 16;
    const int vr = tid >> 3, vc0 = (tid & 7) * 16;

    // prologue: stage tile tstart
    bf16x8 kA, kB, vA, vB;
    {
        const bf16_t* ksrc = K + base + (size_t)(tstart * 128 + kr) * 64 + kc0;
        kA = *reinterpret_cast<const bf16x8*>(ksrc);
        kB = *reinterpret_cast<const bf16x8*>(ksrc + 8);
        const bf16_t* vsrc = Vt + base + (size_t)vr * T_DIM + tstart * 128 + vc0;
        vA = *reinterpret_cast<const bf16x8*>(vsrc);
        vB = *reinterpret_cast<const bf16x8*>(vsrc + 8);
        *reinterpret_cast<bf16x8*>(&Ks[kr][kc0])     = kA;
        *reinterpret_cast<bf16x8*>(&Ks[kr][kc0 + 8]) = kB;
        *reinterpret_cast<bf16x8*>(&Vs[vr][vc0])     = vA;
        *reinterpret_cast<bf16x8*>(&Vs[vr][vc0 + 8]) = vB;
    }
    __syncthreads();

    float mreg = -INFINITY, lrow = 0.f;
    f32x4 o[4] = {};                              // o[db]: d = db*16+lg*4+r, q = lr

    for (int it = 0; it < 16; ++it) {
        const bool more = (it + 1) < 16;
        if (more) {                               // T14: issue next-tile loads now
            const int nt = (tstart + it + 1) & 15;
            const bf16_t* ksrc = K + base + (size_t)(nt * 128 + kr) * 64 + kc0;
            kA = *reinterpret_cast<const bf16x8*>(ksrc);
            kB = *reinterpret_cast<const bf16x8*>(ksrc + 8);
            const bf16_t* vsrc = Vt + base + (size_t)vr * T_DIM + nt * 128 + vc0;
            vA = *reinterpret_cast<const bf16x8*>(vsrc);
            vB = *reinterpret_cast<const bf16x8*>(vsrc + 8);
        }

        // S^T = mfma(K, Q): lane -> q = lr, s = kb*16 + lg*4 + r
        f32x4 s[8] = {};
        __builtin_amdgcn_s_setprio(1);
        #pragma unroll
        for (int kb = 0; kb < 8; ++kb)
            #pragma unroll
            for (int kc = 0; kc < 2; ++kc) {
                bf16x8 ak = *reinterpret_cast<const bf16x8*>(&Ks[kb * 16 + lr][kc * 32 + lg * 8]);
                s[kb] = __builtin_amdgcn_mfma_f32_16x16x32_bf16(ak, bq[kc], s[kb], 0, 0, 0);
            }
        __builtin_amdgcn_s_setprio(0);

        // row max (own 32, then across lg-groups); nested for v_max3 fusion
        float pmax = -INFINITY;
        #pragma unroll
        for (int kb = 0; kb < 8; ++kb)
            pmax = fmaxf(pmax,
                   fmaxf(fmaxf(s[kb][0], s[kb][1]), fmaxf(s[kb][2], s[kb][3])));
        pmax = fmaxf(pmax, __shfl_xor(pmax, 16));
        pmax = fmaxf(pmax, __shfl_xor(pmax, 32));

        if (__any(pmax > mreg + 11.5f)) {         // defer-max (log2 domain)
            float newm = fmaxf(mreg, pmax);
            float alpha = fast_exp2(mreg - newm);
            mreg = newm;
            lrow *= alpha;
            #pragma unroll
            for (int db = 0; db < 4; ++db) o[db] *= alpha;   // q = lr: lane-local
        }

        // P = exp2(s - m); row sum; pack to wave-local LDS
        float rs = 0.f;
        #pragma unroll
        for (int kb = 0; kb < 8; ++kb) {
            bf16x4 t4;
            #pragma unroll
            for (int r = 0; r < 4; ++r) {
                float pv = fast_exp2(s[kb][r] - mreg);
                rs += pv;
                t4[r] = (bf16_t)pv;
            }
            *reinterpret_cast<bf16x4*>(&Ps[wid][lr][kb * 16 + lg * 4]) = t4;
        }
        rs += __shfl_xor(rs, 16);
        rs += __shfl_xor(rs, 32);
        lrow += rs;

        // O^T += V^T P^T: swapped PV -> lane holds d = db*16+lg*4+r, q = lr
        __builtin_amdgcn_s_setprio(1);
        #pragma unroll
        for (int sc = 0; sc < 4; ++sc) {
            bf16x8 bp = *reinterpret_cast<const bf16x8*>(&Ps[wid][lr][sc * 32 + lg * 8]);
            #pragma unroll
            for (int db = 0; db < 4; ++db) {
                bf16x8 av = *reinterpret_cast<const bf16x8*>(&Vs[db * 16 + lr][sc * 32 + lg * 8]);
                o[db] = __builtin_amdgcn_mfma_f32_16x16x32_bf16(av, bp, o[db], 0, 0, 0);
            }
        }
        __builtin_amdgcn_s_setprio(0);
        __syncthreads();                          // all reads of Ks/Vs done

        if (more) {                               // write prefetched regs -> LDS
            *reinterpret_cast<bf16x8*>(&Ks[kr][kc0])     = kA;
            *reinterpret_cast<bf16x8*>(&Ks[kr][kc0 + 8]) = kB;
            *reinterpret_cast<bf16x8*>(&Vs[vr][vc0])     = vA;
            *reinterpret_cast<bf16x8*>(&Vs[vr][vc0 + 8]) = vB;
        }
        __syncthreads();                          // staging visible
    }

    // epilogue: q = lr is lane-local -> no shuffles
    const float linv = 1.f / lrow;
    const int t = q0 + wid * 16 + lr;
    const size_t rowbase = ((size_t)b_idx * T_DIM + t) * E_DIM + h * 64;
    #pragma unroll
    for (int db = 0; db < 4; ++db) {
        bf16x4 t4;
        #pragma unroll
        for (int r = 0; r < 4; ++r) t4[r] = (bf16_t)(o[db][r] * linv);
        *reinterpret_cast<bf16x4*>(&Aw[rowbase + db * 16 + lg * 4]) = t4;
    }
}

// ---------------------------------------------------------------------------
// Output GEMM: [4096 x 1024 x 1024], swapped -> float4 stores, 2-phase dbuf.
// ---------------------------------------------------------------------------
__global__ __launch_bounds__(256) void out_gemm_kernel(
    const bf16_t* __restrict__ Aw, const bf16_t* __restrict__ Wgt,
    const float* __restrict__ bsum, float* __restrict__ out) {
    const int p = blockIdx.x;                    // 256 blocks
    const int l = (p & 7) * 32 + (p >> 3);
    const int mx = l & 31, ny = l >> 5;
    const int m0 = mx * 128, n0 = ny * 128;

    __shared__ bf16_t As[2][128][32];
    __shared__ bf16_t Bs[2][128][32];

    const int tid = threadIdx.x;
    const int lane = tid & 63, wid = tid >> 6;
    const int wr = wid >> 1, wc = wid & 1;
    const int lr = lane & 15, lg = lane >> 4;
    const int srow = lane >> 2, scol = (lane & 3) * 8;

    f32x4 acc[4][4] = {};

    #define STAGE_O(buf, k0)                                                       \
        _Pragma("unroll")                                                          \
        for (int j = 0; j < 2; ++j) {                                              \
            load_lds16(Aw + (size_t)(m0 + wid * 32 + j * 16 + srow) * E_DIM + (k0) + scol, \
                       (char*)&As[buf][0][0] + wid * 2048 + j * 1024);             \
            load_lds16(Wgt + (size_t)(n0 + wid * 32 + j * 16 + srow) * E_DIM + (k0) + scol, \
                       (char*)&Bs[buf][0][0] + wid * 2048 + j * 1024);             \
        }

    STAGE_O(0, 0);
    for (int t = 0; t < 32; ++t) {
        __syncthreads();
        if (t < 31) STAGE_O((t + 1) & 1, (t + 1) * 32);
        const int b = t & 1;
        bf16x8 a[4], bb[4];
        #pragma unroll
        for (int i = 0; i < 4; ++i)
            a[i] = *reinterpret_cast<const bf16x8*>(&As[b][wr * 64 + i * 16 + lr][lg * 8]);
        #pragma unroll
        for (int j = 0; j < 4; ++j)
            bb[j] = *reinterpret_cast<const bf16x8*>(&Bs[b][wc * 64 + j * 16 + lr][lg * 8]);
        __builtin_amdgcn_s_setprio(1);
        #pragma unroll
        for (int j = 0; j < 4; ++j)
            #pragma unroll
            for (int i = 0; i < 4; ++i)
                acc[j][i] = __builtin_amdgcn_mfma_f32_16x16x32_bf16(bb[j], a[i], acc[j][i], 0, 0, 0);
        __builtin_amdgcn_s_setprio(0);
    }
    #undef STAGE_O

    #pragma unroll
    for (int j = 0; j < 4; ++j) {
        const int e = n0 + wc * 64 + j * 16 + lg * 4;
        const float4 bs4 = *reinterpret_cast<const float4*>(&bsum[e]);
        #pragma unroll
        for (int i = 0; i < 4; ++i) {
            const int m = m0 + wr * 64 + i * 16 + lr;
            float4 o4;
            o4.x = acc[j][i][0] + bs4.x;
            o4.y = acc[j][i][1] + bs4.y;
            o4.z = acc[j][i][2] + bs4.z;
            o4.w = acc[j][i][3] + bs4.w;
            *reinterpret_cast<float4*>(&out[(size_t)m * E_DIM + e]) = o4;
        }
    }
}

// ---------------------------------------------------------------------------
extern "C" void kernel_launch(void* const* d_in, const int* in_sizes, int n_in,
                              void* d_out, int out_size, void* d_ws, size_t ws_size,
                              hipStream_t stream) {
    const float* hs   = (const float*)d_in[0];
    const float* Wq   = (const float*)d_in[1];
    const float* bq   = (const float*)d_in[2];
    const float* Wk   = (const float*)d_in[3];
    const float* bk   = (const float*)d_in[4];
    const float* Wv   = (const float*)d_in[5];
    const float* bv   = (const float*)d_in[6];
    const float* Wo   = (const float*)d_in[7];
    const float* bo   = (const float*)d_in[8];
    const float* gate = (const float*)d_in[9];
    float* out = (float*)d_out;

    const size_t NX = (size_t)M_TOT * E_DIM;           // 4M elems
    const size_t NW = (size_t)H_DIM * D_DIM * E_DIM;   // 1M elems
    bf16_t* p = (bf16_t*)d_ws;
    bf16_t* Xb   = p; p += NX;
    bf16_t* Wcat = p; p += 3 * NW;
    bf16_t* Wgt  = p; p += NW;
    bf16_t* Qw   = p; p += NX;
    bf16_t* Kw   = p; p += NX;
    bf16_t* Vtw  = p; p += NX;
    bf16_t* Aw   = p; p += NX;
    float*  bsum = (float*)p;

    cast_x_kernel<<<dim3(NX / 2048), 256, 0, stream>>>(hs, Xb);
    wqkv_t_kernel<<<dim3(16, 16, 3), 256, 0, stream>>>(Wq, Wk, Wv, Wcat);
    wo_t_kernel<<<dim3(16, 16), 256, 0, stream>>>(Wo, gate, Wgt);
    bias_sum_kernel<<<dim3(4), 256, 0, stream>>>(bo, gate, bsum);

    qk_gemm_kernel<<<dim3(512), 256, 0, stream>>>(Xb, Wcat, bq, bk, Qw, Kw);
    v_gemm_kernel<<<dim3(256), 256, 0, stream>>>(Xb, Wcat, bv, Vtw);

    attn_mfma_kernel<<<dim3(512), 512, 0, stream>>>(Qw, Kw, Vtw, Aw);

    out_gemm_kernel<<<dim3(256), 256, 0, stream>>>(Aw, Wgt, bsum, out);
}

// Round 7
// 205.500 us; speedup vs baseline: 1.2200x; 1.1960x over previous
//
#include <hip/hip_runtime.h>
#include <math.h>

#define E_DIM 1024
#define H_DIM 16
#define D_DIM 64
#define B_DIM 2
#define T_DIM 2048
#define M_TOT (B_DIM * T_DIM)   // 4096

typedef __bf16 bf16_t;
typedef bf16_t bf16x4 __attribute__((ext_vector_type(4)));
typedef bf16_t bf16x8 __attribute__((ext_vector_type(8)));
typedef float f32x4 __attribute__((ext_vector_type(4)));

#define LOG2E_DIV8 0.18033688011112042f   // 0.125 * log2(e)

__device__ __forceinline__ float fast_exp2(float x) {
#if __has_builtin(__builtin_amdgcn_exp2f)
    return __builtin_amdgcn_exp2f(x);     // single v_exp_f32
#else
    return __expf(x * 0.6931471805599453f);
#endif
}

__device__ __forceinline__ void load_lds16(const void* g, void* l) {
    __builtin_amdgcn_global_load_lds(
        (const __attribute__((address_space(1))) unsigned int*)g,
        (__attribute__((address_space(3))) unsigned int*)l, 16, 0, 0);
}

// ---------------------------------------------------------------------------
// Fused prep: blocks [0,2048) cast X; [2048,2816) transpose Wq/Wk/Wv;
// [2816,3072) transpose+gate Wo; [3072,3076) bias sum. One launch.
// ---------------------------------------------------------------------------
__global__ __launch_bounds__(256) void prep_kernel(
    const float* __restrict__ x,
    const float* __restrict__ Wq, const float* __restrict__ Wk,
    const float* __restrict__ Wv, const float* __restrict__ Wo,
    const float* __restrict__ bo, const float* __restrict__ gate,
    bf16_t* __restrict__ Xb, bf16_t* __restrict__ Wcat,
    bf16_t* __restrict__ Wgt, float* __restrict__ bsum) {
    __shared__ float Tt[64][65];
    const int b = blockIdx.x;
    const int tid = threadIdx.x;

    if (b < 2048) {                               // cast fp32 -> bf16
        size_t i = ((size_t)b * 256 + tid) * 8;
        float4 a0 = *reinterpret_cast<const float4*>(x + i);
        float4 a1 = *reinterpret_cast<const float4*>(x + i + 4);
        bf16x8 o;
        o[0] = (bf16_t)a0.x; o[1] = (bf16_t)a0.y; o[2] = (bf16_t)a0.z; o[3] = (bf16_t)a0.w;
        o[4] = (bf16_t)a1.x; o[5] = (bf16_t)a1.y; o[6] = (bf16_t)a1.z; o[7] = (bf16_t)a1.w;
        *reinterpret_cast<bf16x8*>(Xb + i) = o;
    } else if (b < 2816) {                        // Wq/Wk/Wv [H][E][D] -> [z*16+h][D][E]
        const int idx = b - 2048;
        const int z = idx >> 8;
        const int rem = idx & 255;
        const int h = rem >> 4, et = rem & 15;
        const float* W = z == 0 ? Wq : (z == 1 ? Wk : Wv);
        const int r = tid >> 2, c4 = (tid & 3) * 16;
        const float* src = W + (size_t)h * 65536 + (size_t)(et * 64 + r) * 64 + c4;
        #pragma unroll
        for (int k = 0; k < 16; k += 4) {
            float4 v = *reinterpret_cast<const float4*>(src + k);
            Tt[r][c4 + k + 0] = v.x; Tt[r][c4 + k + 1] = v.y;
            Tt[r][c4 + k + 2] = v.z; Tt[r][c4 + k + 3] = v.w;
        }
        __syncthreads();
        bf16x8 o0, o1;
        #pragma unroll
        for (int k = 0; k < 8; ++k) o0[k] = (bf16_t)Tt[c4 + k][r];
        #pragma unroll
        for (int k = 0; k < 8; ++k) o1[k] = (bf16_t)Tt[c4 + 8 + k][r];
        bf16_t* dst = Wcat + ((size_t)(z * 16 + h) * 64 + r) * 1024 + et * 64 + c4;
        *reinterpret_cast<bf16x8*>(dst) = o0;
        *reinterpret_cast<bf16x8*>(dst + 8) = o1;
    } else if (b < 3072) {                        // Wo [H][D][E] -> Wgt[e][h*64+d]*gate
        const int idx = b - 2816;
        const int h = idx >> 4, et = idx & 15;
        const float g = gate[h];
        const int r = tid >> 2, c4 = (tid & 3) * 16;
        const float* src = Wo + (size_t)h * 65536 + (size_t)r * 1024 + et * 64 + c4;
        #pragma unroll
        for (int k = 0; k < 16; k += 4) {
            float4 v = *reinterpret_cast<const float4*>(src + k);
            Tt[r][c4 + k + 0] = v.x * g; Tt[r][c4 + k + 1] = v.y * g;
            Tt[r][c4 + k + 2] = v.z * g; Tt[r][c4 + k + 3] = v.w * g;
        }
        __syncthreads();
        bf16x8 o0, o1;
        #pragma unroll
        for (int k = 0; k < 8; ++k) o0[k] = (bf16_t)Tt[c4 + k][r];
        #pragma unroll
        for (int k = 0; k < 8; ++k) o1[k] = (bf16_t)Tt[c4 + 8 + k][r];
        bf16_t* dst = Wgt + (size_t)(et * 64 + r) * 1024 + h * 64 + c4;
        *reinterpret_cast<bf16x8*>(dst) = o0;
        *reinterpret_cast<bf16x8*>(dst + 8) = o1;
    } else {                                      // bsum[e] = sum_h gate[h]*bo[h][e]
        const int e = (b - 3072) * 256 + tid;
        float s = 0.f;
        #pragma unroll
        for (int h = 0; h < H_DIM; ++h) s += gate[h] * bo[h * E_DIM + e];
        bsum[e] = s;
    }
}

// ---------------------------------------------------------------------------
// Fused QKV GEMM: [4096 x 3072 x 1024], 128x128 tiles, BK=32, single-buffer
// stage->sync->mfma->sync loop, 768 blocks = 3/CU.
// z<2 (Q,K): swapped mfma -> bf16x4 [t][d] stores, Q scaled to exp2 domain.
// z==2 (V): unswapped -> bf16x4 stores into transposed Vt[d][t].
// ---------------------------------------------------------------------------
__global__ __launch_bounds__(256) void qkv_gemm_kernel(
    const bf16_t* __restrict__ Xb, const bf16_t* __restrict__ Wcat,
    const float* __restrict__ bqp, const float* __restrict__ bkp,
    const float* __restrict__ bvp,
    bf16_t* __restrict__ Qw, bf16_t* __restrict__ Kw, bf16_t* __restrict__ Vtw) {
    const int p = blockIdx.x;                    // 768 blocks, 768 % 8 == 0
    const int l = (p & 7) * 96 + (p >> 3);       // bijective XCD swizzle
    const int mx = l & 31, ny = l >> 5;
    const int m0 = mx * 128, n0 = ny * 128;
    const int z = n0 >> 10;                      // block-uniform: 0=Q,1=K,2=V

    __shared__ bf16_t As[128][32];
    __shared__ bf16_t Bs[128][32];

    const int tid = threadIdx.x;
    const int lane = tid & 63, wid = tid >> 6;
    const int wr = wid >> 1, wc = wid & 1;
    const int lr = lane & 15, lg = lane >> 4;
    const int srow = lane >> 2, scol = (lane & 3) * 8;

    const int b_idx = m0 >> 11;
    const int t00 = m0 & (T_DIM - 1);

    #define QKV_STAGE(k0)                                                          \
        _Pragma("unroll")                                                          \
        for (int j = 0; j < 2; ++j) {                                              \
            load_lds16(Xb + (size_t)(m0 + wid * 32 + j * 16 + srow) * E_DIM + (k0) + scol, \
                       (char*)&As[0][0] + wid * 2048 + j * 1024);                  \
            load_lds16(Wcat + (size_t)(n0 + wid * 32 + j * 16 + srow) * E_DIM + (k0) + scol, \
                       (char*)&Bs[0][0] + wid * 2048 + j * 1024);                  \
        }
    #define QKV_FRAGS                                                              \
        bf16x8 a[4], bb[4];                                                        \
        _Pragma("unroll")                                                          \
        for (int i = 0; i < 4; ++i)                                                \
            a[i] = *reinterpret_cast<const bf16x8*>(&As[wr * 64 + i * 16 + lr][lg * 8]); \
        _Pragma("unroll")                                                          \
        for (int j = 0; j < 4; ++j)                                                \
            bb[j] = *reinterpret_cast<const bf16x8*>(&Bs[wc * 64 + j * 16 + lr][lg * 8]);

    if (z < 2) {   // ---- Q/K path: swapped mfma, C[n][m] ----
        f32x4 acc[4][4] = {};
        for (int k0 = 0; k0 < E_DIM; k0 += 32) {
            QKV_STAGE(k0);
            __syncthreads();
            QKV_FRAGS;
            __builtin_amdgcn_s_setprio(1);
            #pragma unroll
            for (int j = 0; j < 4; ++j)
                #pragma unroll
                for (int i = 0; i < 4; ++i)
                    acc[j][i] = __builtin_amdgcn_mfma_f32_16x16x32_bf16(bb[j], a[i], acc[j][i], 0, 0, 0);
            __builtin_amdgcn_s_setprio(0);
            __syncthreads();
        }
        const float scale = (z == 0) ? LOG2E_DIV8 : 1.0f;
        const float* bias = (z == 0) ? bqp : bkp;
        bf16_t* Obase = (z == 0) ? Qw : Kw;
        #pragma unroll
        for (int j = 0; j < 4; ++j) {
            const int n = n0 + wc * 64 + j * 16 + lg * 4;      // + r
            const int h = (n >> 6) & 15;
            const int dbase = n & 63;
            const float4 bv4 = *reinterpret_cast<const float4*>(&bias[n & 1023]);
            bf16_t* O = Obase + (size_t)(b_idx * H_DIM + h) * T_DIM * 64;
            #pragma unroll
            for (int i = 0; i < 4; ++i) {
                const int t = t00 + wr * 64 + i * 16 + lr;
                bf16x4 t4;
                #pragma unroll
                for (int r = 0; r < 4; ++r)
                    t4[r] = (bf16_t)((acc[j][i][r] + (&bv4.x)[r]) * scale);
                *reinterpret_cast<bf16x4*>(&O[(size_t)t * 64 + dbase]) = t4;
            }
        }
    } else {       // ---- V path: unswapped, C[m][n] -> transposed store ----
        f32x4 acc[4][4] = {};
        for (int k0 = 0; k0 < E_DIM; k0 += 32) {
            QKV_STAGE(k0);
            __syncthreads();
            QKV_FRAGS;
            __builtin_amdgcn_s_setprio(1);
            #pragma unroll
            for (int i = 0; i < 4; ++i)
                #pragma unroll
                for (int j = 0; j < 4; ++j)
                    acc[i][j] = __builtin_amdgcn_mfma_f32_16x16x32_bf16(a[i], bb[j], acc[i][j], 0, 0, 0);
            __builtin_amdgcn_s_setprio(0);
            __syncthreads();
        }
        #pragma unroll
        for (int j = 0; j < 4; ++j) {
            const int n = n0 + wc * 64 + j * 16 + lr;
            const int h = (n >> 6) & 15;
            const int d = n & 63;
            const float bval = bvp[n & 1023];
            bf16_t* O = Vtw + (size_t)(b_idx * H_DIM + h) * 64 * T_DIM + (size_t)d * T_DIM;
            #pragma unroll
            for (int i = 0; i < 4; ++i) {
                const int t = t00 + wr * 64 + i * 16 + lg * 4;
                bf16x4 t4;
                #pragma unroll
                for (int r = 0; r < 4; ++r) t4[r] = (bf16_t)(acc[i][j][r] + bval);
                *reinterpret_cast<bf16x4*>(&O[t]) = t4;
            }
        }
    }
    #undef QKV_STAGE
    #undef QKV_FRAGS
}

// ---------------------------------------------------------------------------
// Flash attention: 8 waves x 16 q-rows, KVBLK=128, swapped QK^T + swapped PV
// (q = lane&15 lane-local: no shuffles for rescale/normalize), exp2-domain
// softmax, defer-max, XCD swizzle. Staging is fully inside the two barriers
// (proven R2/R3 structure — no cross-barrier register prefetch).
// ---------------------------------------------------------------------------
__global__ __launch_bounds__(512, 4) void attn_mfma_kernel(
    const bf16_t* __restrict__ Q, const bf16_t* __restrict__ K,
    const bf16_t* __restrict__ Vt, bf16_t* __restrict__ Aw) {
    const int p = blockIdx.x;                    // 512 blocks
    const int l = (p & 7) * 64 + (p >> 3);       // XCD swizzle: 4 heads/XCD
    const int qx = l & 15, bh = l >> 4;
    const int b_idx = bh >> 4, h = bh & 15;
    const int q0 = qx * 128;
    const size_t base = (size_t)bh * T_DIM * 64;

    __shared__ bf16_t Ks[128][72];
    __shared__ bf16_t Vs[64][136];
    __shared__ bf16_t Ps[8][16][136];

    const int tid = threadIdx.x;
    const int lane = tid & 63;
    const int wid = tid >> 6;
    const int lr = lane & 15, lg = lane >> 4;

    // Q fragments (B-operand of QK^T): lane holds Q[q0+wid*16+lr][kc*32+lg*8..]
    bf16x8 bq[2];
    #pragma unroll
    for (int kc = 0; kc < 2; ++kc)
        bq[kc] = *reinterpret_cast<const bf16x8*>(
            Q + base + (size_t)(q0 + wid * 16 + lr) * 64 + kc * 32 + lg * 8);

    const int kr = tid >> 2, kc0 = (tid & 3) * 16;
    const int vr = tid >> 3, vc0 = (tid & 7) * 16;

    float mreg = -INFINITY, lrow = 0.f;
    f32x4 o[4] = {};                              // o[db]: d = db*16+lg*4+r, q = lr

    for (int s0 = 0; s0 < T_DIM; s0 += 128) {
        {   // stage K (128x64) and V^T (64x128): global -> regs -> padded LDS
            const bf16_t* ksrc = K + base + (size_t)(s0 + kr) * 64 + kc0;
            bf16x8 k0 = *reinterpret_cast<const bf16x8*>(ksrc);
            bf16x8 k1 = *reinterpret_cast<const bf16x8*>(ksrc + 8);
            const bf16_t* vsrc = Vt + base + (size_t)vr * T_DIM + s0 + vc0;
            bf16x8 v0 = *reinterpret_cast<const bf16x8*>(vsrc);
            bf16x8 v1 = *reinterpret_cast<const bf16x8*>(vsrc + 8);
            *reinterpret_cast<bf16x8*>(&Ks[kr][kc0])     = k0;
            *reinterpret_cast<bf16x8*>(&Ks[kr][kc0 + 8]) = k1;
            *reinterpret_cast<bf16x8*>(&Vs[vr][vc0])     = v0;
            *reinterpret_cast<bf16x8*>(&Vs[vr][vc0 + 8]) = v1;
        }
        __syncthreads();

        // S^T = mfma(K, Q): lane -> q = lr, s = kb*16 + lg*4 + r
        f32x4 s[8] = {};
        __builtin_amdgcn_s_setprio(1);
        #pragma unroll
        for (int kb = 0; kb < 8; ++kb)
            #pragma unroll
            for (int kc = 0; kc < 2; ++kc) {
                bf16x8 ak = *reinterpret_cast<const bf16x8*>(&Ks[kb * 16 + lr][kc * 32 + lg * 8]);
                s[kb] = __builtin_amdgcn_mfma_f32_16x16x32_bf16(ak, bq[kc], s[kb], 0, 0, 0);
            }
        __builtin_amdgcn_s_setprio(0);

        // row max over own 32 values, then across the 4 lg-groups
        float pmax = -INFINITY;
        #pragma unroll
        for (int kb = 0; kb < 8; ++kb)
            pmax = fmaxf(pmax,
                   fmaxf(fmaxf(s[kb][0], s[kb][1]), fmaxf(s[kb][2], s[kb][3])));
        pmax = fmaxf(pmax, __shfl_xor(pmax, 16));
        pmax = fmaxf(pmax, __shfl_xor(pmax, 32));

        if (__any(pmax > mreg + 11.5f)) {         // defer-max (log2 domain)
            float newm = fmaxf(mreg, pmax);
            float alpha = fast_exp2(mreg - newm);
            mreg = newm;
            lrow *= alpha;
            #pragma unroll
            for (int db = 0; db < 4; ++db) o[db] *= alpha;   // q = lr: lane-local
        }

        // P = exp2(s - m); row sum; pack to wave-local LDS
        float rs = 0.f;
        #pragma unroll
        for (int kb = 0; kb < 8; ++kb) {
            bf16x4 t4;
            #pragma unroll
            for (int r = 0; r < 4; ++r) {
                float pv = fast_exp2(s[kb][r] - mreg);
                rs += pv;
                t4[r] = (bf16_t)pv;
            }
            *reinterpret_cast<bf16x4*>(&Ps[wid][lr][kb * 16 + lg * 4]) = t4;
        }
        rs += __shfl_xor(rs, 16);
        rs += __shfl_xor(rs, 32);
        lrow += rs;

        // O^T += V^T P^T: swapped PV -> lane holds d = db*16+lg*4+r, q = lr
        __builtin_amdgcn_s_setprio(1);
        #pragma unroll
        for (int sc = 0; sc < 4; ++sc) {
            bf16x8 bp = *reinterpret_cast<const bf16x8*>(&Ps[wid][lr][sc * 32 + lg * 8]);
            #pragma unroll
            for (int db = 0; db < 4; ++db) {
                bf16x8 av = *reinterpret_cast<const bf16x8*>(&Vs[db * 16 + lr][sc * 32 + lg * 8]);
                o[db] = __builtin_amdgcn_mfma_f32_16x16x32_bf16(av, bp, o[db], 0, 0, 0);
            }
        }
        __builtin_amdgcn_s_setprio(0);
        __syncthreads();                          // all reads done before next stage
    }

    // epilogue: q = lr is lane-local -> no shuffles
    const float linv = 1.f / lrow;
    const int t = q0 + wid * 16 + lr;
    const size_t rowbase = ((size_t)b_idx * T_DIM + t) * E_DIM + h * 64;
    #pragma unroll
    for (int db = 0; db < 4; ++db) {
        bf16x4 t4;
        #pragma unroll
        for (int r = 0; r < 4; ++r) t4[r] = (bf16_t)(o[db][r] * linv);
        *reinterpret_cast<bf16x4*>(&Aw[rowbase + db * 16 + lg * 4]) = t4;
    }
}

// ---------------------------------------------------------------------------
// Output GEMM: [4096 x 1024 x 1024], 128x64 tiles -> 512 blocks (2/CU),
// single-buffer loop, swapped mfma -> float4 stores.
// ---------------------------------------------------------------------------
__global__ __launch_bounds__(256) void out_gemm_kernel(
    const bf16_t* __restrict__ Aw, const bf16_t* __restrict__ Wgt,
    const float* __restrict__ bsum, float* __restrict__ out) {
    const int p = blockIdx.x;                    // 512 blocks
    const int l = (p & 7) * 64 + (p >> 3);
    const int mx = l & 31, ny = l >> 5;          // 32 m-tiles x 16 n-tiles
    const int m0 = mx * 128, n0 = ny * 64;

    __shared__ bf16_t As[128][32];
    __shared__ bf16_t Bs[64][32];

    const int tid = threadIdx.x;
    const int lane = tid & 63, wid = tid >> 6;
    const int wr = wid >> 1, wc = wid & 1;       // wave tile: 64m x 32n
    const int lr = lane & 15, lg = lane >> 4;
    const int srow = lane >> 2, scol = (lane & 3) * 8;

    f32x4 acc[2][4] = {};                        // [j(n)][i(m)]

    for (int k0 = 0; k0 < E_DIM; k0 += 32) {
        #pragma unroll
        for (int j = 0; j < 2; ++j)
            load_lds16(Aw + (size_t)(m0 + wid * 32 + j * 16 + srow) * E_DIM + k0 + scol,
                       (char*)&As[0][0] + wid * 2048 + j * 1024);
        load_lds16(Wgt + (size_t)(n0 + wid * 16 + srow) * E_DIM + k0 + scol,
                   (char*)&Bs[0][0] + wid * 1024);
        __syncthreads();
        bf16x8 a[4], bb[2];
        #pragma unroll
        for (int i = 0; i < 4; ++i)
            a[i] = *reinterpret_cast<const bf16x8*>(&As[wr * 64 + i * 16 + lr][lg * 8]);
        #pragma unroll
        for (int j = 0; j < 2; ++j)
            bb[j] = *reinterpret_cast<const bf16x8*>(&Bs[wc * 32 + j * 16 + lr][lg * 8]);
        __builtin_amdgcn_s_setprio(1);
        #pragma unroll
        for (int j = 0; j < 2; ++j)
            #pragma unroll
            for (int i = 0; i < 4; ++i)
                acc[j][i] = __builtin_amdgcn_mfma_f32_16x16x32_bf16(bb[j], a[i], acc[j][i], 0, 0, 0);
        __builtin_amdgcn_s_setprio(0);
        __syncthreads();
    }

    #pragma unroll
    for (int j = 0; j < 2; ++j) {
        const int e = n0 + wc * 32 + j * 16 + lg * 4;
        const float4 bs4 = *reinterpret_cast<const float4*>(&bsum[e]);
        #pragma unroll
        for (int i = 0; i < 4; ++i) {
            const int m = m0 + wr * 64 + i * 16 + lr;
            float4 o4;
            o4.x = acc[j][i][0] + bs4.x;
            o4.y = acc[j][i][1] + bs4.y;
            o4.z = acc[j][i][2] + bs4.z;
            o4.w = acc[j][i][3] + bs4.w;
            *reinterpret_cast<float4*>(&out[(size_t)m * E_DIM + e]) = o4;
        }
    }
}

// ---------------------------------------------------------------------------
extern "C" void kernel_launch(void* const* d_in, const int* in_sizes, int n_in,
                              void* d_out, int out_size, void* d_ws, size_t ws_size,
                              hipStream_t stream) {
    const float* hs   = (const float*)d_in[0];
    const float* Wq   = (const float*)d_in[1];
    const float* bq   = (const float*)d_in[2];
    const float* Wk   = (const float*)d_in[3];
    const float* bk   = (const float*)d_in[4];
    const float* Wv   = (const float*)d_in[5];
    const float* bv   = (const float*)d_in[6];
    const float* Wo   = (const float*)d_in[7];
    const float* bo   = (const float*)d_in[8];
    const float* gate = (const float*)d_in[9];
    float* out = (float*)d_out;

    const size_t NX = (size_t)M_TOT * E_DIM;           // 4M elems
    const size_t NW = (size_t)H_DIM * D_DIM * E_DIM;   // 1M elems
    bf16_t* p = (bf16_t*)d_ws;
    bf16_t* Xb   = p; p += NX;
    bf16_t* Wcat = p; p += 3 * NW;
    bf16_t* Wgt  = p; p += NW;
    bf16_t* Qw   = p; p += NX;
    bf16_t* Kw   = p; p += NX;
    bf16_t* Vtw  = p; p += NX;
    bf16_t* Aw   = p; p += NX;
    float*  bsum = (float*)p;

    prep_kernel<<<dim3(3076), 256, 0, stream>>>(hs, Wq, Wk, Wv, Wo, bo, gate,
                                                Xb, Wcat, Wgt, bsum);

    qkv_gemm_kernel<<<dim3(768), 256, 0, stream>>>(Xb, Wcat, bq, bk, bv, Qw, Kw, Vtw);

    attn_mfma_kernel<<<dim3(512), 512, 0, stream>>>(Qw, Kw, Vtw, Aw);

    out_gemm_kernel<<<dim3(512), 256, 0, stream>>>(Aw, Wgt, bsum, out);
}

// Round 8
// 203.796 us; speedup vs baseline: 1.2302x; 1.0084x over previous
//
#include <hip/hip_runtime.h>
#include <math.h>

#define E_DIM 1024
#define H_DIM 16
#define D_DIM 64
#define B_DIM 2
#define T_DIM 2048
#define M_TOT (B_DIM * T_DIM)   // 4096

typedef __bf16 bf16_t;
typedef bf16_t bf16x2 __attribute__((ext_vector_type(2)));
typedef bf16_t bf16x4 __attribute__((ext_vector_type(4)));
typedef bf16_t bf16x8 __attribute__((ext_vector_type(8)));
typedef float f32x4 __attribute__((ext_vector_type(4)));
typedef float f32x16 __attribute__((ext_vector_type(16)));
typedef unsigned int uint4v __attribute__((ext_vector_type(4)));

#define LOG2E_DIV8 0.18033688011112042f   // 0.125 * log2(e)

__device__ __forceinline__ float fast_exp2(float x) {
#if __has_builtin(__builtin_amdgcn_exp2f)
    return __builtin_amdgcn_exp2f(x);     // single v_exp_f32
#else
    return __expf(x * 0.6931471805599453f);
#endif
}

__device__ __forceinline__ unsigned pack_bf16x2(float a, float b) {
    bf16x2 t = {(bf16_t)a, (bf16_t)b};
    return __builtin_bit_cast(unsigned, t);
}

// hi-pair (lane <-> lane+32) half-swap, permlane32_swap semantics via shfl:
// a' = {a (lanes<32), b_from_partner (lanes>=32)}
// b' = {a_from_partner (lanes<32), b (lanes>=32)}
__device__ __forceinline__ void swap32(unsigned& a, unsigned& b, int hi) {
    unsigned as = (unsigned)__shfl_xor((int)a, 32);
    unsigned bs = (unsigned)__shfl_xor((int)b, 32);
    unsigned na = hi ? bs : a;
    unsigned nb = hi ? b : as;
    a = na; b = nb;
}

__device__ __forceinline__ void load_lds16(const void* g, void* l) {
    __builtin_amdgcn_global_load_lds(
        (const __attribute__((address_space(1))) unsigned int*)g,
        (__attribute__((address_space(3))) unsigned int*)l, 16, 0, 0);
}

// ---------------------------------------------------------------------------
// Fused prep: blocks [0,2048) cast X; [2048,2816) transpose Wq/Wk/Wv;
// [2816,3072) transpose+gate Wo; [3072,3076) bias sum. One launch.
// ---------------------------------------------------------------------------
__global__ __launch_bounds__(256) void prep_kernel(
    const float* __restrict__ x,
    const float* __restrict__ Wq, const float* __restrict__ Wk,
    const float* __restrict__ Wv, const float* __restrict__ Wo,
    const float* __restrict__ bo, const float* __restrict__ gate,
    bf16_t* __restrict__ Xb, bf16_t* __restrict__ Wcat,
    bf16_t* __restrict__ Wgt, float* __restrict__ bsum) {
    __shared__ float Tt[64][65];
    const int b = blockIdx.x;
    const int tid = threadIdx.x;

    if (b < 2048) {                               // cast fp32 -> bf16
        size_t i = ((size_t)b * 256 + tid) * 8;
        float4 a0 = *reinterpret_cast<const float4*>(x + i);
        float4 a1 = *reinterpret_cast<const float4*>(x + i + 4);
        bf16x8 o;
        o[0] = (bf16_t)a0.x; o[1] = (bf16_t)a0.y; o[2] = (bf16_t)a0.z; o[3] = (bf16_t)a0.w;
        o[4] = (bf16_t)a1.x; o[5] = (bf16_t)a1.y; o[6] = (bf16_t)a1.z; o[7] = (bf16_t)a1.w;
        *reinterpret_cast<bf16x8*>(Xb + i) = o;
    } else if (b < 2816) {                        // Wq/Wk/Wv [H][E][D] -> [z*16+h][D][E]
        const int idx = b - 2048;
        const int z = idx >> 8;
        const int rem = idx & 255;
        const int h = rem >> 4, et = rem & 15;
        const float* W = z == 0 ? Wq : (z == 1 ? Wk : Wv);
        const int r = tid >> 2, c4 = (tid & 3) * 16;
        const float* src = W + (size_t)h * 65536 + (size_t)(et * 64 + r) * 64 + c4;
        #pragma unroll
        for (int k = 0; k < 16; k += 4) {
            float4 v = *reinterpret_cast<const float4*>(src + k);
            Tt[r][c4 + k + 0] = v.x; Tt[r][c4 + k + 1] = v.y;
            Tt[r][c4 + k + 2] = v.z; Tt[r][c4 + k + 3] = v.w;
        }
        __syncthreads();
        bf16x8 o0, o1;
        #pragma unroll
        for (int k = 0; k < 8; ++k) o0[k] = (bf16_t)Tt[c4 + k][r];
        #pragma unroll
        for (int k = 0; k < 8; ++k) o1[k] = (bf16_t)Tt[c4 + 8 + k][r];
        bf16_t* dst = Wcat + ((size_t)(z * 16 + h) * 64 + r) * 1024 + et * 64 + c4;
        *reinterpret_cast<bf16x8*>(dst) = o0;
        *reinterpret_cast<bf16x8*>(dst + 8) = o1;
    } else if (b < 3072) {                        // Wo [H][D][E] -> Wgt[e][h*64+d]*gate
        const int idx = b - 2816;
        const int h = idx >> 4, et = idx & 15;
        const float g = gate[h];
        const int r = tid >> 2, c4 = (tid & 3) * 16;
        const float* src = Wo + (size_t)h * 65536 + (size_t)r * 1024 + et * 64 + c4;
        #pragma unroll
        for (int k = 0; k < 16; k += 4) {
            float4 v = *reinterpret_cast<const float4*>(src + k);
            Tt[r][c4 + k + 0] = v.x * g; Tt[r][c4 + k + 1] = v.y * g;
            Tt[r][c4 + k + 2] = v.z * g; Tt[r][c4 + k + 3] = v.w * g;
        }
        __syncthreads();
        bf16x8 o0, o1;
        #pragma unroll
        for (int k = 0; k < 8; ++k) o0[k] = (bf16_t)Tt[c4 + k][r];
        #pragma unroll
        for (int k = 0; k < 8; ++k) o1[k] = (bf16_t)Tt[c4 + 8 + k][r];
        bf16_t* dst = Wgt + (size_t)(et * 64 + r) * 1024 + h * 64 + c4;
        *reinterpret_cast<bf16x8*>(dst) = o0;
        *reinterpret_cast<bf16x8*>(dst + 8) = o1;
    } else {                                      // bsum[e] = sum_h gate[h]*bo[h][e]
        const int e = (b - 3072) * 256 + tid;
        float s = 0.f;
        #pragma unroll
        for (int h = 0; h < H_DIM; ++h) s += gate[h] * bo[h * E_DIM + e];
        bsum[e] = s;
    }
}

// ---------------------------------------------------------------------------
// Fused QKV GEMM (unchanged from R7): [4096 x 3072 x 1024], 128x128 tiles,
// BK=32, single-buffer stage->sync->mfma->sync, 768 blocks.
// ---------------------------------------------------------------------------
__global__ __launch_bounds__(256) void qkv_gemm_kernel(
    const bf16_t* __restrict__ Xb, const bf16_t* __restrict__ Wcat,
    const float* __restrict__ bqp, const float* __restrict__ bkp,
    const float* __restrict__ bvp,
    bf16_t* __restrict__ Qw, bf16_t* __restrict__ Kw, bf16_t* __restrict__ Vtw) {
    const int p = blockIdx.x;                    // 768 blocks, 768 % 8 == 0
    const int l = (p & 7) * 96 + (p >> 3);       // bijective XCD swizzle
    const int mx = l & 31, ny = l >> 5;
    const int m0 = mx * 128, n0 = ny * 128;
    const int z = n0 >> 10;                      // block-uniform: 0=Q,1=K,2=V

    __shared__ bf16_t As[128][32];
    __shared__ bf16_t Bs[128][32];

    const int tid = threadIdx.x;
    const int lane = tid & 63, wid = tid >> 6;
    const int wr = wid >> 1, wc = wid & 1;
    const int lr = lane & 15, lg = lane >> 4;
    const int srow = lane >> 2, scol = (lane & 3) * 8;

    const int b_idx = m0 >> 11;
    const int t00 = m0 & (T_DIM - 1);

    #define QKV_STAGE(k0)                                                          \
        _Pragma("unroll")                                                          \
        for (int j = 0; j < 2; ++j) {                                              \
            load_lds16(Xb + (size_t)(m0 + wid * 32 + j * 16 + srow) * E_DIM + (k0) + scol, \
                       (char*)&As[0][0] + wid * 2048 + j * 1024);                  \
            load_lds16(Wcat + (size_t)(n0 + wid * 32 + j * 16 + srow) * E_DIM + (k0) + scol, \
                       (char*)&Bs[0][0] + wid * 2048 + j * 1024);                  \
        }
    #define QKV_FRAGS                                                              \
        bf16x8 a[4], bb[4];                                                        \
        _Pragma("unroll")                                                          \
        for (int i = 0; i < 4; ++i)                                                \
            a[i] = *reinterpret_cast<const bf16x8*>(&As[wr * 64 + i * 16 + lr][lg * 8]); \
        _Pragma("unroll")                                                          \
        for (int j = 0; j < 4; ++j)                                                \
            bb[j] = *reinterpret_cast<const bf16x8*>(&Bs[wc * 64 + j * 16 + lr][lg * 8]);

    if (z < 2) {   // ---- Q/K path: swapped mfma, C[n][m] ----
        f32x4 acc[4][4] = {};
        for (int k0 = 0; k0 < E_DIM; k0 += 32) {
            QKV_STAGE(k0);
            __syncthreads();
            QKV_FRAGS;
            __builtin_amdgcn_s_setprio(1);
            #pragma unroll
            for (int j = 0; j < 4; ++j)
                #pragma unroll
                for (int i = 0; i < 4; ++i)
                    acc[j][i] = __builtin_amdgcn_mfma_f32_16x16x32_bf16(bb[j], a[i], acc[j][i], 0, 0, 0);
            __builtin_amdgcn_s_setprio(0);
            __syncthreads();
        }
        const float scale = (z == 0) ? LOG2E_DIV8 : 1.0f;
        const float* bias = (z == 0) ? bqp : bkp;
        bf16_t* Obase = (z == 0) ? Qw : Kw;
        #pragma unroll
        for (int j = 0; j < 4; ++j) {
            const int n = n0 + wc * 64 + j * 16 + lg * 4;      // + r
            const int h = (n >> 6) & 15;
            const int dbase = n & 63;
            const float4 bv4 = *reinterpret_cast<const float4*>(&bias[n & 1023]);
            bf16_t* O = Obase + (size_t)(b_idx * H_DIM + h) * T_DIM * 64;
            #pragma unroll
            for (int i = 0; i < 4; ++i) {
                const int t = t00 + wr * 64 + i * 16 + lr;
                bf16x4 t4;
                #pragma unroll
                for (int r = 0; r < 4; ++r)
                    t4[r] = (bf16_t)((acc[j][i][r] + (&bv4.x)[r]) * scale);
                *reinterpret_cast<bf16x4*>(&O[(size_t)t * 64 + dbase]) = t4;
            }
        }
    } else {       // ---- V path: unswapped, C[m][n] -> transposed store ----
        f32x4 acc[4][4] = {};
        for (int k0 = 0; k0 < E_DIM; k0 += 32) {
            QKV_STAGE(k0);
            __syncthreads();
            QKV_FRAGS;
            __builtin_amdgcn_s_setprio(1);
            #pragma unroll
            for (int i = 0; i < 4; ++i)
                #pragma unroll
                for (int j = 0; j < 4; ++j)
                    acc[i][j] = __builtin_amdgcn_mfma_f32_16x16x32_bf16(a[i], bb[j], acc[i][j], 0, 0, 0);
            __builtin_amdgcn_s_setprio(0);
            __syncthreads();
        }
        #pragma unroll
        for (int j = 0; j < 4; ++j) {
            const int n = n0 + wc * 64 + j * 16 + lr;
            const int h = (n >> 6) & 15;
            const int d = n & 63;
            const float bval = bvp[n & 1023];
            bf16_t* O = Vtw + (size_t)(b_idx * H_DIM + h) * 64 * T_DIM + (size_t)d * T_DIM;
            #pragma unroll
            for (int i = 0; i < 4; ++i) {
                const int t = t00 + wr * 64 + i * 16 + lg * 4;
                bf16x4 t4;
                #pragma unroll
                for (int r = 0; r < 4; ++r) t4[r] = (bf16_t)(acc[i][j][r] + bval);
                *reinterpret_cast<bf16x4*>(&O[t]) = t4;
            }
        }
    }
    #undef QKV_STAGE
    #undef QKV_FRAGS
}

// ---------------------------------------------------------------------------
// Flash attention, 32x32 MFMA + fully in-register softmax (guide §B / m214):
// 4 waves x 32 q-rows (QBLK=128), KVBLK=64. Swapped QK^T: S^T=mfma(K,Q) puts
// q = lane&31 lane-local. P never touches LDS: dword packs redistributed to
// the PV B-operand layout with one hi-pair (lane+-32) half-swap per dword
// pair (T12, shfl emulation of permlane32_swap). Swapped PV keeps q
// lane-local in O. exp2-domain softmax, defer-max (THR=11.5 log2).
//
// Layouts (HW-verified, guide §3): C/D: col=lane&31, row=(reg&3)+8(reg>>2)+
// 4*(lane>>5); A: m=lane&31, k=8*(lane>>5)+j; B: n=lane&31, k=8*(lane>>5)+j.
// ---------------------------------------------------------------------------
__global__ __launch_bounds__(256, 3) void attn_mfma_kernel(
    const bf16_t* __restrict__ Q, const bf16_t* __restrict__ K,
    const bf16_t* __restrict__ Vt, bf16_t* __restrict__ Aw) {
    const int p = blockIdx.x;                    // 512 blocks
    const int l = (p & 7) * 64 + (p >> 3);       // XCD swizzle: 4 heads/XCD
    const int qx = l & 15, bh = l >> 4;
    const int b_idx = bh >> 4, h = bh & 15;
    const int q0 = qx * 128;
    const size_t base = (size_t)bh * T_DIM * 64;

    __shared__ bf16_t Ks[64][72];                // [s][d], 144B rows (16B-aligned)
    __shared__ bf16_t Vs[64][72];                // [d][s]

    const int tid = threadIdx.x;
    const int lane = tid & 63;
    const int w = tid >> 6;                      // 0..3
    const int lq = lane & 31;                    // q (and s-row / d-row) index
    const int hi = lane >> 5;                    // k-half select

    // Q B-operand frags: B[k=8hi+j][n=lq] = Q[qrow][kc*16 + 8hi + j]
    const int qrow = q0 + w * 32 + lq;
    bf16x8 qb[4];
    #pragma unroll
    for (int kc = 0; kc < 4; ++kc)
        qb[kc] = *reinterpret_cast<const bf16x8*>(
            Q + base + (size_t)qrow * 64 + kc * 16 + hi * 8);

    // staging indices: 256 threads, 64 rows x 4 col-chunks of 16 elements
    const int sr = tid >> 2, sc = (tid & 3) * 16;

    float mreg = -INFINITY, lrow = 0.f;
    f32x16 o[2] = {};                            // o[db]: d=db*32+(r&3)+8(r>>2)+4hi, q=lq

    for (int s0 = 0; s0 < T_DIM; s0 += 64) {
        {   // stage K (64x64) and V^T (64x64): global -> regs -> padded LDS
            const bf16_t* ksrc = K + base + (size_t)(s0 + sr) * 64 + sc;
            bf16x8 k0 = *reinterpret_cast<const bf16x8*>(ksrc);
            bf16x8 k1 = *reinterpret_cast<const bf16x8*>(ksrc + 8);
            const bf16_t* vsrc = Vt + base + (size_t)sr * T_DIM + s0 + sc;
            bf16x8 v0 = *reinterpret_cast<const bf16x8*>(vsrc);
            bf16x8 v1 = *reinterpret_cast<const bf16x8*>(vsrc + 8);
            *reinterpret_cast<bf16x8*>(&Ks[sr][sc])     = k0;
            *reinterpret_cast<bf16x8*>(&Ks[sr][sc + 8]) = k1;
            *reinterpret_cast<bf16x8*>(&Vs[sr][sc])     = v0;
            *reinterpret_cast<bf16x8*>(&Vs[sr][sc + 8]) = v1;
        }
        __syncthreads();

        // S^T = mfma(K, Q): lane reg r of s32[sb] holds
        // S[q=lq][s = s0 + sb*32 + (r&3) + 8*(r>>2) + 4*hi]
        f32x16 s32[2] = {};
        __builtin_amdgcn_s_setprio(1);
        #pragma unroll
        for (int sb = 0; sb < 2; ++sb)
            #pragma unroll
            for (int kc = 0; kc < 4; ++kc) {
                bf16x8 ka = *reinterpret_cast<const bf16x8*>(
                    &Ks[sb * 32 + lq][kc * 16 + hi * 8]);
                s32[sb] = __builtin_amdgcn_mfma_f32_32x32x16_bf16(ka, qb[kc], s32[sb], 0, 0, 0);
            }
        __builtin_amdgcn_s_setprio(0);

        // row max: own 32 values + hi-pair exchange
        float pmax = -INFINITY;
        #pragma unroll
        for (int sb = 0; sb < 2; ++sb)
            #pragma unroll
            for (int r = 0; r < 16; r += 4)
                pmax = fmaxf(pmax, fmaxf(fmaxf(s32[sb][r], s32[sb][r + 1]),
                                         fmaxf(s32[sb][r + 2], s32[sb][r + 3])));
        pmax = fmaxf(pmax, __shfl_xor(pmax, 32));

        if (__any(pmax > mreg + 11.5f)) {        // defer-max (log2 domain)
            float newm = fmaxf(mreg, pmax);
            float alpha = fast_exp2(mreg - newm);
            mreg = newm;
            lrow *= alpha;
            o[0] *= alpha;                       // q = lq: lane-local rescale
            o[1] *= alpha;
        }

        // P = exp2(s - m), packed to dwords W[sb][grp][i] = (q2=2i, 2i+1)
        float rs = 0.f;
        unsigned W[2][4][2];
        #pragma unroll
        for (int sb = 0; sb < 2; ++sb)
            #pragma unroll
            for (int grp = 0; grp < 4; ++grp) {
                float p0 = fast_exp2(s32[sb][grp * 4 + 0] - mreg);
                float p1 = fast_exp2(s32[sb][grp * 4 + 1] - mreg);
                float p2 = fast_exp2(s32[sb][grp * 4 + 2] - mreg);
                float p3 = fast_exp2(s32[sb][grp * 4 + 3] - mreg);
                rs += (p0 + p1) + (p2 + p3);
                W[sb][grp][0] = pack_bf16x2(p0, p1);
                W[sb][grp][1] = pack_bf16x2(p2, p3);
            }
        rs += __shfl_xor(rs, 32);
        lrow += rs;

        // redistribute to PV B-operand frags: pa[ks][j] = P[q=lq][16ks+8hi+j]
        bf16x8 pa[4];
        #pragma unroll
        for (int sb = 0; sb < 2; ++sb)
            #pragma unroll
            for (int kl = 0; kl < 2; ++kl) {
                unsigned a0 = W[sb][2 * kl][0], b0 = W[sb][2 * kl + 1][0];
                unsigned a1 = W[sb][2 * kl][1], b1 = W[sb][2 * kl + 1][1];
                swap32(a0, b0, hi);              // a0 -> dword0, b0 -> dword2
                swap32(a1, b1, hi);              // a1 -> dword1, b1 -> dword3
                uint4v tv = {a0, a1, b0, b1};
                pa[sb * 2 + kl] = __builtin_bit_cast(bf16x8, tv);
            }

        // O^T += V^T P^T: o[db] = mfma(A=V^T, B=pa) -> q stays lane-local
        __builtin_amdgcn_s_setprio(1);
        #pragma unroll
        for (int ks = 0; ks < 4; ++ks)
            #pragma unroll
            for (int db = 0; db < 2; ++db) {
                bf16x8 va = *reinterpret_cast<const bf16x8*>(
                    &Vs[db * 32 + lq][ks * 16 + hi * 8]);
                o[db] = __builtin_amdgcn_mfma_f32_32x32x16_bf16(va, pa[ks], o[db], 0, 0, 0);
            }
        __builtin_amdgcn_s_setprio(0);
        __syncthreads();                         // all reads done before next stage
    }

    // epilogue: q = lq lane-local; reg r -> d = db*32 + 8*(r>>2) + 4hi + (r&3)
    const float linv = 1.f / lrow;
    const size_t rowbase = ((size_t)b_idx * T_DIM + qrow) * E_DIM + h * 64;
    #pragma unroll
    for (int db = 0; db < 2; ++db)
        #pragma unroll
        for (int grp = 0; grp < 4; ++grp) {
            bf16x4 t4;
            #pragma unroll
            for (int i = 0; i < 4; ++i)
                t4[i] = (bf16_t)(o[db][grp * 4 + i] * linv);
            *reinterpret_cast<bf16x4*>(
                &Aw[rowbase + db * 32 + grp * 8 + hi * 4]) = t4;
        }
}

// ---------------------------------------------------------------------------
// Output GEMM (unchanged from R7): [4096 x 1024 x 1024], 128x64 tiles ->
// 512 blocks, single-buffer loop, swapped mfma -> float4 stores.
// ---------------------------------------------------------------------------
__global__ __launch_bounds__(256) void out_gemm_kernel(
    const bf16_t* __restrict__ Aw, const bf16_t* __restrict__ Wgt,
    const float* __restrict__ bsum, float* __restrict__ out) {
    const int p = blockIdx.x;                    // 512 blocks
    const int l = (p & 7) * 64 + (p >> 3);
    const int mx = l & 31, ny = l >> 5;          // 32 m-tiles x 16 n-tiles
    const int m0 = mx * 128, n0 = ny * 64;

    __shared__ bf16_t As[128][32];
    __shared__ bf16_t Bs[64][32];

    const int tid = threadIdx.x;
    const int lane = tid & 63, wid = tid >> 6;
    const int wr = wid >> 1, wc = wid & 1;       // wave tile: 64m x 32n
    const int lr = lane & 15, lg = lane >> 4;
    const int srow = lane >> 2, scol = (lane & 3) * 8;

    f32x4 acc[2][4] = {};                        // [j(n)][i(m)]

    for (int k0 = 0; k0 < E_DIM; k0 += 32) {
        #pragma unroll
        for (int j = 0; j < 2; ++j)
            load_lds16(Aw + (size_t)(m0 + wid * 32 + j * 16 + srow) * E_DIM + k0 + scol,
                       (char*)&As[0][0] + wid * 2048 + j * 1024);
        load_lds16(Wgt + (size_t)(n0 + wid * 16 + srow) * E_DIM + k0 + scol,
                   (char*)&Bs[0][0] + wid * 1024);
        __syncthreads();
        bf16x8 a[4], bb[2];
        #pragma unroll
        for (int i = 0; i < 4; ++i)
            a[i] = *reinterpret_cast<const bf16x8*>(&As[wr * 64 + i * 16 + lr][lg * 8]);
        #pragma unroll
        for (int j = 0; j < 2; ++j)
            bb[j] = *reinterpret_cast<const bf16x8*>(&Bs[wc * 32 + j * 16 + lr][lg * 8]);
        __builtin_amdgcn_s_setprio(1);
        #pragma unroll
        for (int j = 0; j < 2; ++j)
            #pragma unroll
            for (int i = 0; i < 4; ++i)
                acc[j][i] = __builtin_amdgcn_mfma_f32_16x16x32_bf16(bb[j], a[i], acc[j][i], 0, 0, 0);
        __builtin_amdgcn_s_setprio(0);
        __syncthreads();
    }

    #pragma unroll
    for (int j = 0; j < 2; ++j) {
        const int e = n0 + wc * 32 + j * 16 + lg * 4;
        const float4 bs4 = *reinterpret_cast<const float4*>(&bsum[e]);
        #pragma unroll
        for (int i = 0; i < 4; ++i) {
            const int m = m0 + wr * 64 + i * 16 + lr;
            float4 o4;
            o4.x = acc[j][i][0] + bs4.x;
            o4.y = acc[j][i][1] + bs4.y;
            o4.z = acc[j][i][2] + bs4.z;
            o4.w = acc[j][i][3] + bs4.w;
            *reinterpret_cast<float4*>(&out[(size_t)m * E_DIM + e]) = o4;
        }
    }
}

// ---------------------------------------------------------------------------
extern "C" void kernel_launch(void* const* d_in, const int* in_sizes, int n_in,
                              void* d_out, int out_size, void* d_ws, size_t ws_size,
                              hipStream_t stream) {
    const float* hs   = (const float*)d_in[0];
    const float* Wq   = (const float*)d_in[1];
    const float* bq   = (const float*)d_in[2];
    const float* Wk   = (const float*)d_in[3];
    const float* bk   = (const float*)d_in[4];
    const float* Wv   = (const float*)d_in[5];
    const float* bv   = (const float*)d_in[6];
    const float* Wo   = (const float*)d_in[7];
    const float* bo   = (const float*)d_in[8];
    const float* gate = (const float*)d_in[9];
    float* out = (float*)d_out;

    const size_t NX = (size_t)M_TOT * E_DIM;           // 4M elems
    const size_t NW = (size_t)H_DIM * D_DIM * E_DIM;   // 1M elems
    bf16_t* p = (bf16_t*)d_ws;
    bf16_t* Xb   = p; p += NX;
    bf16_t* Wcat = p; p += 3 * NW;
    bf16_t* Wgt  = p; p += NW;
    bf16_t* Qw   = p; p += NX;
    bf16_t* Kw   = p; p += NX;
    bf16_t* Vtw  = p; p += NX;
    bf16_t* Aw   = p; p += NX;
    float*  bsum = (float*)p;

    prep_kernel<<<dim3(3076), 256, 0, stream>>>(hs, Wq, Wk, Wv, Wo, bo, gate,
                                                Xb, Wcat, Wgt, bsum);

    qkv_gemm_kernel<<<dim3(768), 256, 0, stream>>>(Xb, Wcat, bq, bk, bv, Qw, Kw, Vtw);

    attn_mfma_kernel<<<dim3(512), 256, 0, stream>>>(Qw, Kw, Vtw, Aw);

    out_gemm_kernel<<<dim3(512), 256, 0, stream>>>(Aw, Wgt, bsum, out);
}

// Round 9
// 198.146 us; speedup vs baseline: 1.2652x; 1.0285x over previous
//
#include <hip/hip_runtime.h>
#include <math.h>

#define E_DIM 1024
#define H_DIM 16
#define D_DIM 64
#define B_DIM 2
#define T_DIM 2048
#define M_TOT (B_DIM * T_DIM)   // 4096

typedef __bf16 bf16_t;
typedef bf16_t bf16x2 __attribute__((ext_vector_type(2)));
typedef bf16_t bf16x4 __attribute__((ext_vector_type(4)));
typedef bf16_t bf16x8 __attribute__((ext_vector_type(8)));
typedef float f32x4 __attribute__((ext_vector_type(4)));
typedef float f32x16 __attribute__((ext_vector_type(16)));
typedef unsigned int uint4v __attribute__((ext_vector_type(4)));

#define LOG2E_DIV8 0.18033688011112042f   // 0.125 * log2(e)

__device__ __forceinline__ float fast_exp2(float x) {
#if __has_builtin(__builtin_amdgcn_exp2f)
    return __builtin_amdgcn_exp2f(x);     // single v_exp_f32
#else
    return __expf(x * 0.6931471805599453f);
#endif
}

__device__ __forceinline__ unsigned pack_bf16x2(float a, float b) {
    bf16x2 t = {(bf16_t)a, (bf16_t)b};
    return __builtin_bit_cast(unsigned, t);
}

// hi-pair (lane <-> lane+32) half-swap (permlane32_swap semantics via shfl)
__device__ __forceinline__ void swap32(unsigned& a, unsigned& b, int hi) {
    unsigned as = (unsigned)__shfl_xor((int)a, 32);
    unsigned bs = (unsigned)__shfl_xor((int)b, 32);
    unsigned na = hi ? bs : a;
    unsigned nb = hi ? b : as;
    a = na; b = nb;
}

__device__ __forceinline__ void load_lds16(const void* g, void* l) {
    __builtin_amdgcn_global_load_lds(
        (const __attribute__((address_space(1))) unsigned int*)g,
        (__attribute__((address_space(3))) unsigned int*)l, 16, 0, 0);
}

// ---------------------------------------------------------------------------
// Fused prep: blocks [0,2048) cast X; [2048,2816) transpose Wq/Wk/Wv;
// [2816,3072) transpose+gate Wo; [3072,3076) bias sum. One launch.
// ---------------------------------------------------------------------------
__global__ __launch_bounds__(256) void prep_kernel(
    const float* __restrict__ x,
    const float* __restrict__ Wq, const float* __restrict__ Wk,
    const float* __restrict__ Wv, const float* __restrict__ Wo,
    const float* __restrict__ bo, const float* __restrict__ gate,
    bf16_t* __restrict__ Xb, bf16_t* __restrict__ Wcat,
    bf16_t* __restrict__ Wgt, float* __restrict__ bsum) {
    __shared__ float Tt[64][65];
    const int b = blockIdx.x;
    const int tid = threadIdx.x;

    if (b < 2048) {                               // cast fp32 -> bf16
        size_t i = ((size_t)b * 256 + tid) * 8;
        float4 a0 = *reinterpret_cast<const float4*>(x + i);
        float4 a1 = *reinterpret_cast<const float4*>(x + i + 4);
        bf16x8 o;
        o[0] = (bf16_t)a0.x; o[1] = (bf16_t)a0.y; o[2] = (bf16_t)a0.z; o[3] = (bf16_t)a0.w;
        o[4] = (bf16_t)a1.x; o[5] = (bf16_t)a1.y; o[6] = (bf16_t)a1.z; o[7] = (bf16_t)a1.w;
        *reinterpret_cast<bf16x8*>(Xb + i) = o;
    } else if (b < 2816) {                        // Wq/Wk/Wv [H][E][D] -> [z*16+h][D][E]
        const int idx = b - 2048;
        const int z = idx >> 8;
        const int rem = idx & 255;
        const int h = rem >> 4, et = rem & 15;
        const float* W = z == 0 ? Wq : (z == 1 ? Wk : Wv);
        const int r = tid >> 2, c4 = (tid & 3) * 16;
        const float* src = W + (size_t)h * 65536 + (size_t)(et * 64 + r) * 64 + c4;
        #pragma unroll
        for (int k = 0; k < 16; k += 4) {
            float4 v = *reinterpret_cast<const float4*>(src + k);
            Tt[r][c4 + k + 0] = v.x; Tt[r][c4 + k + 1] = v.y;
            Tt[r][c4 + k + 2] = v.z; Tt[r][c4 + k + 3] = v.w;
        }
        __syncthreads();
        bf16x8 o0, o1;
        #pragma unroll
        for (int k = 0; k < 8; ++k) o0[k] = (bf16_t)Tt[c4 + k][r];
        #pragma unroll
        for (int k = 0; k < 8; ++k) o1[k] = (bf16_t)Tt[c4 + 8 + k][r];
        bf16_t* dst = Wcat + ((size_t)(z * 16 + h) * 64 + r) * 1024 + et * 64 + c4;
        *reinterpret_cast<bf16x8*>(dst) = o0;
        *reinterpret_cast<bf16x8*>(dst + 8) = o1;
    } else if (b < 3072) {                        // Wo [H][D][E] -> Wgt[e][h*64+d]*gate
        const int idx = b - 2816;
        const int h = idx >> 4, et = idx & 15;
        const float g = gate[h];
        const int r = tid >> 2, c4 = (tid & 3) * 16;
        const float* src = Wo + (size_t)h * 65536 + (size_t)r * 1024 + et * 64 + c4;
        #pragma unroll
        for (int k = 0; k < 16; k += 4) {
            float4 v = *reinterpret_cast<const float4*>(src + k);
            Tt[r][c4 + k + 0] = v.x * g; Tt[r][c4 + k + 1] = v.y * g;
            Tt[r][c4 + k + 2] = v.z * g; Tt[r][c4 + k + 3] = v.w * g;
        }
        __syncthreads();
        bf16x8 o0, o1;
        #pragma unroll
        for (int k = 0; k < 8; ++k) o0[k] = (bf16_t)Tt[c4 + k][r];
        #pragma unroll
        for (int k = 0; k < 8; ++k) o1[k] = (bf16_t)Tt[c4 + 8 + k][r];
        bf16_t* dst = Wgt + (size_t)(et * 64 + r) * 1024 + h * 64 + c4;
        *reinterpret_cast<bf16x8*>(dst) = o0;
        *reinterpret_cast<bf16x8*>(dst + 8) = o1;
    } else {                                      // bsum[e] = sum_h gate[h]*bo[h][e]
        const int e = (b - 3072) * 256 + tid;
        float s = 0.f;
        #pragma unroll
        for (int h = 0; h < H_DIM; ++h) s += gate[h] * bo[h * E_DIM + e];
        bsum[e] = s;
    }
}

// ---------------------------------------------------------------------------
// Fused QKV GEMM (unchanged): [4096 x 3072 x 1024], 128x128 tiles, BK=32,
// single-buffer stage->sync->mfma->sync, 768 blocks.
// ---------------------------------------------------------------------------
__global__ __launch_bounds__(256) void qkv_gemm_kernel(
    const bf16_t* __restrict__ Xb, const bf16_t* __restrict__ Wcat,
    const float* __restrict__ bqp, const float* __restrict__ bkp,
    const float* __restrict__ bvp,
    bf16_t* __restrict__ Qw, bf16_t* __restrict__ Kw, bf16_t* __restrict__ Vtw) {
    const int p = blockIdx.x;                    // 768 blocks, 768 % 8 == 0
    const int l = (p & 7) * 96 + (p >> 3);       // bijective XCD swizzle
    const int mx = l & 31, ny = l >> 5;
    const int m0 = mx * 128, n0 = ny * 128;
    const int z = n0 >> 10;                      // block-uniform: 0=Q,1=K,2=V

    __shared__ bf16_t As[128][32];
    __shared__ bf16_t Bs[128][32];

    const int tid = threadIdx.x;
    const int lane = tid & 63, wid = tid >> 6;
    const int wr = wid >> 1, wc = wid & 1;
    const int lr = lane & 15, lg = lane >> 4;
    const int srow = lane >> 2, scol = (lane & 3) * 8;

    const int b_idx = m0 >> 11;
    const int t00 = m0 & (T_DIM - 1);

    #define QKV_STAGE(k0)                                                          \
        _Pragma("unroll")                                                          \
        for (int j = 0; j < 2; ++j) {                                              \
            load_lds16(Xb + (size_t)(m0 + wid * 32 + j * 16 + srow) * E_DIM + (k0) + scol, \
                       (char*)&As[0][0] + wid * 2048 + j * 1024);                  \
            load_lds16(Wcat + (size_t)(n0 + wid * 32 + j * 16 + srow) * E_DIM + (k0) + scol, \
                       (char*)&Bs[0][0] + wid * 2048 + j * 1024);                  \
        }
    #define QKV_FRAGS                                                              \
        bf16x8 a[4], bb[4];                                                        \
        _Pragma("unroll")                                                          \
        for (int i = 0; i < 4; ++i)                                                \
            a[i] = *reinterpret_cast<const bf16x8*>(&As[wr * 64 + i * 16 + lr][lg * 8]); \
        _Pragma("unroll")                                                          \
        for (int j = 0; j < 4; ++j)                                                \
            bb[j] = *reinterpret_cast<const bf16x8*>(&Bs[wc * 64 + j * 16 + lr][lg * 8]);

    if (z < 2) {   // ---- Q/K path: swapped mfma, C[n][m] ----
        f32x4 acc[4][4] = {};
        for (int k0 = 0; k0 < E_DIM; k0 += 32) {
            QKV_STAGE(k0);
            __syncthreads();
            QKV_FRAGS;
            __builtin_amdgcn_s_setprio(1);
            #pragma unroll
            for (int j = 0; j < 4; ++j)
                #pragma unroll
                for (int i = 0; i < 4; ++i)
                    acc[j][i] = __builtin_amdgcn_mfma_f32_16x16x32_bf16(bb[j], a[i], acc[j][i], 0, 0, 0);
            __builtin_amdgcn_s_setprio(0);
            __syncthreads();
        }
        const float scale = (z == 0) ? LOG2E_DIV8 : 1.0f;
        const float* bias = (z == 0) ? bqp : bkp;
        bf16_t* Obase = (z == 0) ? Qw : Kw;
        #pragma unroll
        for (int j = 0; j < 4; ++j) {
            const int n = n0 + wc * 64 + j * 16 + lg * 4;      // + r
            const int h = (n >> 6) & 15;
            const int dbase = n & 63;
            const float4 bv4 = *reinterpret_cast<const float4*>(&bias[n & 1023]);
            bf16_t* O = Obase + (size_t)(b_idx * H_DIM + h) * T_DIM * 64;
            #pragma unroll
            for (int i = 0; i < 4; ++i) {
                const int t = t00 + wr * 64 + i * 16 + lr;
                bf16x4 t4;
                #pragma unroll
                for (int r = 0; r < 4; ++r)
                    t4[r] = (bf16_t)((acc[j][i][r] + (&bv4.x)[r]) * scale);
                *reinterpret_cast<bf16x4*>(&O[(size_t)t * 64 + dbase]) = t4;
            }
        }
    } else {       // ---- V path: unswapped, C[m][n] -> transposed store ----
        f32x4 acc[4][4] = {};
        for (int k0 = 0; k0 < E_DIM; k0 += 32) {
            QKV_STAGE(k0);
            __syncthreads();
            QKV_FRAGS;
            __builtin_amdgcn_s_setprio(1);
            #pragma unroll
            for (int i = 0; i < 4; ++i)
                #pragma unroll
                for (int j = 0; j < 4; ++j)
                    acc[i][j] = __builtin_amdgcn_mfma_f32_16x16x32_bf16(a[i], bb[j], acc[i][j], 0, 0, 0);
            __builtin_amdgcn_s_setprio(0);
            __syncthreads();
        }
        #pragma unroll
        for (int j = 0; j < 4; ++j) {
            const int n = n0 + wc * 64 + j * 16 + lr;
            const int h = (n >> 6) & 15;
            const int d = n & 63;
            const float bval = bvp[n & 1023];
            bf16_t* O = Vtw + (size_t)(b_idx * H_DIM + h) * 64 * T_DIM + (size_t)d * T_DIM;
            #pragma unroll
            for (int i = 0; i < 4; ++i) {
                const int t = t00 + wr * 64 + i * 16 + lg * 4;
                bf16x4 t4;
                #pragma unroll
                for (int r = 0; r < 4; ++r) t4[r] = (bf16_t)(acc[i][j][r] + bval);
                *reinterpret_cast<bf16x4*>(&O[t]) = t4;
            }
        }
    }
    #undef QKV_STAGE
    #undef QKV_FRAGS
}

// ---------------------------------------------------------------------------
// Flash attention, 32x32 MFMA + in-register softmax, KVBLK=128, LDS
// double-buffer with ONE barrier per tile: next tile's global loads issue at
// loop top (latency hides under QK^T+softmax+PV), ds_write to the OTHER
// buffer after PV, barrier. Load-issue and LDS-write are within the same
// barrier interval (no cross-barrier register hazard, unlike R6).
// Swapped QK^T / swapped PV keep q = lane&31 lane-local throughout.
// ---------------------------------------------------------------------------
__global__ __launch_bounds__(256, 2) void attn_mfma_kernel(
    const bf16_t* __restrict__ Q, const bf16_t* __restrict__ K,
    const bf16_t* __restrict__ Vt, bf16_t* __restrict__ Aw) {
    const int p = blockIdx.x;                    // 512 blocks
    const int l = (p & 7) * 64 + (p >> 3);       // XCD swizzle: 4 heads/XCD
    const int qx = l & 15, bh = l >> 4;
    const int b_idx = bh >> 4, h = bh & 15;
    const int q0 = qx * 128;
    const size_t base = (size_t)bh * T_DIM * 64;

    __shared__ bf16_t Ks[2][128][72];            // [buf][s][d]
    __shared__ bf16_t Vs[2][64][136];            // [buf][d][s]

    const int tid = threadIdx.x;
    const int lane = tid & 63;
    const int w = tid >> 6;                      // 0..3
    const int lq = lane & 31;                    // q (and s-row / d-row) index
    const int hi = lane >> 5;                    // k-half select

    // Q B-operand frags: B[k=8hi+j][n=lq] = Q[qrow][kc*16 + 8hi + j]
    const int qrow = q0 + w * 32 + lq;
    bf16x8 qb[4];
    #pragma unroll
    for (int kc = 0; kc < 4; ++kc)
        qb[kc] = *reinterpret_cast<const bf16x8*>(
            Q + base + (size_t)qrow * 64 + kc * 16 + hi * 8);

    // staging: K 128 rows x 64 (2 thr/row, 64B each); V 64 rows x 128 (4 thr/row)
    const int kr = tid >> 1, kc0 = (tid & 1) * 32;
    const int vr = tid >> 2, vc0 = (tid & 3) * 32;

    bf16x8 kreg[4], vreg[4];
    #define ATT_LOAD(s0)                                                           \
        {   const bf16_t* ksrc = K + base + (size_t)((s0) + kr) * 64 + kc0;        \
            const bf16_t* vsrc = Vt + base + (size_t)vr * T_DIM + (s0) + vc0;      \
            _Pragma("unroll")                                                      \
            for (int j = 0; j < 4; ++j) {                                          \
                kreg[j] = *reinterpret_cast<const bf16x8*>(ksrc + j * 8);          \
                vreg[j] = *reinterpret_cast<const bf16x8*>(vsrc + j * 8);          \
            } }
    #define ATT_WRITE(buf)                                                         \
        {   _Pragma("unroll")                                                      \
            for (int j = 0; j < 4; ++j) {                                          \
                *reinterpret_cast<bf16x8*>(&Ks[buf][kr][kc0 + j * 8]) = kreg[j];   \
                *reinterpret_cast<bf16x8*>(&Vs[buf][vr][vc0 + j * 8]) = vreg[j];   \
            } }

    ATT_LOAD(0);
    ATT_WRITE(0);
    __syncthreads();

    float mreg = -INFINITY, lrow = 0.f;
    f32x16 o[2] = {};                            // o[db]: d=db*32+..., q=lq
    int cur = 0;

    for (int it = 0; it < 16; ++it) {
        if (it < 15) ATT_LOAD((it + 1) * 128);   // issue next-tile loads (in flight)

        // S^T = mfma(K, Q): lane reg r of s32[sb] holds
        // S[q=lq][s = it*128 + sb*32 + (r&3) + 8*(r>>2) + 4*hi]
        f32x16 s32[4] = {};
        __builtin_amdgcn_s_setprio(1);
        #pragma unroll
        for (int sb = 0; sb < 4; ++sb)
            #pragma unroll
            for (int kc = 0; kc < 4; ++kc) {
                bf16x8 ka = *reinterpret_cast<const bf16x8*>(
                    &Ks[cur][sb * 32 + lq][kc * 16 + hi * 8]);
                s32[sb] = __builtin_amdgcn_mfma_f32_32x32x16_bf16(ka, qb[kc], s32[sb], 0, 0, 0);
            }
        __builtin_amdgcn_s_setprio(0);

        // row max: own 64 values + hi-pair exchange
        float pmax = -INFINITY;
        #pragma unroll
        for (int sb = 0; sb < 4; ++sb)
            #pragma unroll
            for (int r = 0; r < 16; r += 4)
                pmax = fmaxf(pmax, fmaxf(fmaxf(s32[sb][r], s32[sb][r + 1]),
                                         fmaxf(s32[sb][r + 2], s32[sb][r + 3])));
        pmax = fmaxf(pmax, __shfl_xor(pmax, 32));

        if (__any(pmax > mreg + 11.5f)) {        // defer-max (log2 domain)
            float newm = fmaxf(mreg, pmax);
            float alpha = fast_exp2(mreg - newm);
            mreg = newm;
            lrow *= alpha;
            o[0] *= alpha;                       // q = lq: lane-local rescale
            o[1] *= alpha;
        }

        // P = exp2(s - m); pack; hi-pair swap -> PV B-operand frags
        float rs = 0.f;
        bf16x8 pa[8];
        #pragma unroll
        for (int sb = 0; sb < 4; ++sb) {
            unsigned Wl[4][2];
            #pragma unroll
            for (int grp = 0; grp < 4; ++grp) {
                float p0 = fast_exp2(s32[sb][grp * 4 + 0] - mreg);
                float p1 = fast_exp2(s32[sb][grp * 4 + 1] - mreg);
                float p2 = fast_exp2(s32[sb][grp * 4 + 2] - mreg);
                float p3 = fast_exp2(s32[sb][grp * 4 + 3] - mreg);
                rs += (p0 + p1) + (p2 + p3);
                Wl[grp][0] = pack_bf16x2(p0, p1);
                Wl[grp][1] = pack_bf16x2(p2, p3);
            }
            #pragma unroll
            for (int kl = 0; kl < 2; ++kl) {
                unsigned a0 = Wl[2 * kl][0], b0 = Wl[2 * kl + 1][0];
                unsigned a1 = Wl[2 * kl][1], b1 = Wl[2 * kl + 1][1];
                swap32(a0, b0, hi);
                swap32(a1, b1, hi);
                uint4v tv = {a0, a1, b0, b1};
                pa[sb * 2 + kl] = __builtin_bit_cast(bf16x8, tv);
            }
        }
        rs += __shfl_xor(rs, 32);
        lrow += rs;

        // O^T += V^T P^T: o[db] = mfma(A=V^T, B=pa) -> q stays lane-local
        __builtin_amdgcn_s_setprio(1);
        #pragma unroll
        for (int ks = 0; ks < 8; ++ks)
            #pragma unroll
            for (int db = 0; db < 2; ++db) {
                bf16x8 va = *reinterpret_cast<const bf16x8*>(
                    &Vs[cur][db * 32 + lq][ks * 16 + hi * 8]);
                o[db] = __builtin_amdgcn_mfma_f32_32x32x16_bf16(va, pa[ks], o[db], 0, 0, 0);
            }
        __builtin_amdgcn_s_setprio(0);

        if (it < 15) ATT_WRITE(cur ^ 1);         // other buffer: no WAR with readers
        __syncthreads();                          // writes visible; readers done
        cur ^= 1;
    }
    #undef ATT_LOAD
    #undef ATT_WRITE

    // epilogue: q = lq lane-local; reg r -> d = db*32 + 8*(r>>2) + 4hi + (r&3)
    const float linv = 1.f / lrow;
    const size_t rowbase = ((size_t)b_idx * T_DIM + qrow) * E_DIM + h * 64;
    #pragma unroll
    for (int db = 0; db < 2; ++db)
        #pragma unroll
        for (int grp = 0; grp < 4; ++grp) {
            bf16x4 t4;
            #pragma unroll
            for (int i = 0; i < 4; ++i)
                t4[i] = (bf16_t)(o[db][grp * 4 + i] * linv);
            *reinterpret_cast<bf16x4*>(
                &Aw[rowbase + db * 32 + grp * 8 + hi * 4]) = t4;
        }
}

// ---------------------------------------------------------------------------
// Output GEMM (unchanged): [4096 x 1024 x 1024], 128x64 tiles -> 512 blocks,
// single-buffer loop, swapped mfma -> float4 stores.
// ---------------------------------------------------------------------------
__global__ __launch_bounds__(256) void out_gemm_kernel(
    const bf16_t* __restrict__ Aw, const bf16_t* __restrict__ Wgt,
    const float* __restrict__ bsum, float* __restrict__ out) {
    const int p = blockIdx.x;                    // 512 blocks
    const int l = (p & 7) * 64 + (p >> 3);
    const int mx = l & 31, ny = l >> 5;          // 32 m-tiles x 16 n-tiles
    const int m0 = mx * 128, n0 = ny * 64;

    __shared__ bf16_t As[128][32];
    __shared__ bf16_t Bs[64][32];

    const int tid = threadIdx.x;
    const int lane = tid & 63, wid = tid >> 6;
    const int wr = wid >> 1, wc = wid & 1;       // wave tile: 64m x 32n
    const int lr = lane & 15, lg = lane >> 4;
    const int srow = lane >> 2, scol = (lane & 3) * 8;

    f32x4 acc[2][4] = {};                        // [j(n)][i(m)]

    for (int k0 = 0; k0 < E_DIM; k0 += 32) {
        #pragma unroll
        for (int j = 0; j < 2; ++j)
            load_lds16(Aw + (size_t)(m0 + wid * 32 + j * 16 + srow) * E_DIM + k0 + scol,
                       (char*)&As[0][0] + wid * 2048 + j * 1024);
        load_lds16(Wgt + (size_t)(n0 + wid * 16 + srow) * E_DIM + k0 + scol,
                   (char*)&Bs[0][0] + wid * 1024);
        __syncthreads();
        bf16x8 a[4], bb[2];
        #pragma unroll
        for (int i = 0; i < 4; ++i)
            a[i] = *reinterpret_cast<const bf16x8*>(&As[wr * 64 + i * 16 + lr][lg * 8]);
        #pragma unroll
        for (int j = 0; j < 2; ++j)
            bb[j] = *reinterpret_cast<const bf16x8*>(&Bs[wc * 32 + j * 16 + lr][lg * 8]);
        __builtin_amdgcn_s_setprio(1);
        #pragma unroll
        for (int j = 0; j < 2; ++j)
            #pragma unroll
            for (int i = 0; i < 4; ++i)
                acc[j][i] = __builtin_amdgcn_mfma_f32_16x16x32_bf16(bb[j], a[i], acc[j][i], 0, 0, 0);
        __builtin_amdgcn_s_setprio(0);
        __syncthreads();
    }

    #pragma unroll
    for (int j = 0; j < 2; ++j) {
        const int e = n0 + wc * 32 + j * 16 + lg * 4;
        const float4 bs4 = *reinterpret_cast<const float4*>(&bsum[e]);
        #pragma unroll
        for (int i = 0; i < 4; ++i) {
            const int m = m0 + wr * 64 + i * 16 + lr;
            float4 o4;
            o4.x = acc[j][i][0] + bs4.x;
            o4.y = acc[j][i][1] + bs4.y;
            o4.z = acc[j][i][2] + bs4.z;
            o4.w = acc[j][i][3] + bs4.w;
            *reinterpret_cast<float4*>(&out[(size_t)m * E_DIM + e]) = o4;
        }
    }
}

// ---------------------------------------------------------------------------
extern "C" void kernel_launch(void* const* d_in, const int* in_sizes, int n_in,
                              void* d_out, int out_size, void* d_ws, size_t ws_size,
                              hipStream_t stream) {
    const float* hs   = (const float*)d_in[0];
    const float* Wq   = (const float*)d_in[1];
    const float* bq   = (const float*)d_in[2];
    const float* Wk   = (const float*)d_in[3];
    const float* bk   = (const float*)d_in[4];
    const float* Wv   = (const float*)d_in[5];
    const float* bv   = (const float*)d_in[6];
    const float* Wo   = (const float*)d_in[7];
    const float* bo   = (const float*)d_in[8];
    const float* gate = (const float*)d_in[9];
    float* out = (float*)d_out;

    const size_t NX = (size_t)M_TOT * E_DIM;           // 4M elems
    const size_t NW = (size_t)H_DIM * D_DIM * E_DIM;   // 1M elems
    bf16_t* p = (bf16_t*)d_ws;
    bf16_t* Xb   = p; p += NX;
    bf16_t* Wcat = p; p += 3 * NW;
    bf16_t* Wgt  = p; p += NW;
    bf16_t* Qw   = p; p += NX;
    bf16_t* Kw   = p; p += NX;
    bf16_t* Vtw  = p; p += NX;
    bf16_t* Aw   = p; p += NX;
    float*  bsum = (float*)p;

    prep_kernel<<<dim3(3076), 256, 0, stream>>>(hs, Wq, Wk, Wv, Wo, bo, gate,
                                                Xb, Wcat, Wgt, bsum);

    qkv_gemm_kernel<<<dim3(768), 256, 0, stream>>>(Xb, Wcat, bq, bk, bv, Qw, Kw, Vtw);

    attn_mfma_kernel<<<dim3(512), 256, 0, stream>>>(Qw, Kw, Vtw, Aw);

    out_gemm_kernel<<<dim3(512), 256, 0, stream>>>(Aw, Wgt, bsum, out);
}